// Round 1
// 358.022 us; speedup vs baseline: 1.0158x; 1.0158x over previous
//
#include <hip/hip_runtime.h>

typedef unsigned short u16;
typedef __attribute__((ext_vector_type(4))) float floatx4;
typedef __attribute__((ext_vector_type(4))) unsigned short u16x4;
typedef __attribute__((ext_vector_type(8))) short short8;
typedef __attribute__((ext_vector_type(8))) __bf16 bf16x8;

#define B_SZ 8
#define C_LEN 2048
#define Q_LEN 512
#define D_DIM 1024
#define K4 (4 * D_DIM)

static __device__ __forceinline__ u16 f2bf(float f) {
    union { float f; unsigned int u; } v; v.f = f;
    unsigned int r = v.u + 0x7FFFu + ((v.u >> 16) & 1u);  // round-to-nearest-even
    return (u16)(r >> 16);
}
static __device__ __forceinline__ float bf2f(u16 h) {
    union { unsigned int u; float f; } v; v.u = ((unsigned int)h) << 16;
    return v.f;
}

// async global->LDS, 16B per lane; LDS dest = wave-uniform base + lane*16
static __device__ __forceinline__ void async16(const void* g, void* l) {
    __builtin_amdgcn_global_load_lds(
        (const __attribute__((address_space(1))) unsigned int*)g,
        (__attribute__((address_space(3))) unsigned int*)(unsigned int)(unsigned long long)l,
        16, 0, 0);
}

// ---------- fused prep: precast_c | precast_q | transpose_q | zero q2c ----------
__global__ __launch_bounds__(256) void prep_kernel(
    const float* __restrict__ c, const float* __restrict__ q,
    const float* __restrict__ w_cq, const float* __restrict__ w_c, const float* __restrict__ w_q,
    u16* __restrict__ cbf, u16* __restrict__ qwbf, u16* __restrict__ qT,
    float* __restrict__ rowterm, float* __restrict__ colterm, float* __restrict__ q2c) {
    int blk = blockIdx.x;
    int tid = threadIdx.x;
    if (blk < 4096) {
        // precast_c: cbf = bf16(c); rowterm = c . w_c
        int row = blk * 4 + (tid >> 6);
        int lane = tid & 63;
        const float* src = c + (size_t)row * D_DIM;
        u16* dst = cbf + (size_t)row * D_DIM;
        float s = 0.f;
        #pragma unroll
        for (int j = 0; j < 4; ++j) {
            int idx = j * 256 + lane * 4;
            floatx4 a = *(const floatx4*)(src + idx);
            floatx4 w = *(const floatx4*)(w_c + idx);
            s += a[0]*w[0] + a[1]*w[1] + a[2]*w[2] + a[3]*w[3];
            u16x4 o;
            #pragma unroll
            for (int e = 0; e < 4; ++e) o[e] = f2bf(a[e]);
            *(u16x4*)(dst + idx) = o;
        }
        for (int off = 32; off; off >>= 1) s += __shfl_down(s, off);
        if (lane == 0) rowterm[row] = s;
    } else if (blk < 5120) {
        // precast_q: qwbf = bf16(q .* w_cq); colterm = q . w_q
        int row = (blk - 4096) * 4 + (tid >> 6);
        int lane = tid & 63;
        const float* src = q + (size_t)row * D_DIM;
        u16* dst = qwbf + (size_t)row * D_DIM;
        float s = 0.f;
        #pragma unroll
        for (int j = 0; j < 4; ++j) {
            int idx = j * 256 + lane * 4;
            floatx4 a  = *(const floatx4*)(src + idx);
            floatx4 wc = *(const floatx4*)(w_cq + idx);
            floatx4 wq = *(const floatx4*)(w_q + idx);
            s += a[0]*wq[0] + a[1]*wq[1] + a[2]*wq[2] + a[3]*wq[3];
            u16x4 o;
            #pragma unroll
            for (int e = 0; e < 4; ++e) o[e] = f2bf(a[e] * wc[e]);
            *(u16x4*)(dst + idx) = o;
        }
        for (int off = 32; off; off >>= 1) s += __shfl_down(s, off);
        if (lane == 0) colterm[row] = s;
    } else if (blk < 9216) {
        // transpose_q: qT[b,d,q] = bf16(q[b,q,d])
        __shared__ float tile[32][33];
        int t = blk - 5120;
        int q0 = (t & 15) * 32;
        int d0 = ((t >> 4) & 31) * 32;
        int b = t >> 9;
        int tx = tid & 31, ty = tid >> 5;  // 32 x 8
        const float* qb = q + (size_t)b * Q_LEN * D_DIM;
        #pragma unroll
        for (int j = 0; j < 4; ++j) {
            int row = ty + j * 8;
            tile[row][tx] = qb[(size_t)(q0 + row) * D_DIM + d0 + tx];
        }
        __syncthreads();
        u16* qTb = qT + (size_t)b * D_DIM * Q_LEN;
        #pragma unroll
        for (int j = 0; j < 4; ++j) {
            int row = ty + j * 8;
            qTb[(size_t)(d0 + row) * Q_LEN + q0 + tx] = f2bf(tile[tx][row]);
        }
    } else {
        // zero q2c (8192 floats)
        int i = (blk - 9216) * 256 + tid;
        q2c[i] = 0.0f;
    }
}

// ---------- fused W prep: Wm[b,n,k] = bf16(W1 + W4*q2c); Wbf[n,kk] = bf16(W[n,1024+kk]) ----------
__global__ __launch_bounds__(256) void wmerge_all(const float* __restrict__ W, const float* __restrict__ q2c,
                                                  u16* __restrict__ Wm, u16* __restrict__ Wbf) {
    int n = blockIdx.x;             // 1024 rows
    int k = threadIdx.x * 4;        // 0..1023
    const float* wr = W + (size_t)n * K4;
    floatx4 w1 = *(const floatx4*)(wr + k);
    floatx4 w4 = *(const floatx4*)(wr + 3072 + k);
    #pragma unroll
    for (int p = 0; p < 2; ++p) {
        int kk = p * 1024 + k;
        floatx4 v = *(const floatx4*)(wr + 1024 + kk);
        u16x4 o;
        #pragma unroll
        for (int e = 0; e < 4; ++e) o[e] = f2bf(v[e]);
        *(u16x4*)(Wbf + (size_t)n * 2048 + kk) = o;
    }
    #pragma unroll
    for (int b = 0; b < 8; ++b) {
        floatx4 g = *(const floatx4*)(q2c + (size_t)b * D_DIM + k);
        u16x4 o;
        #pragma unroll
        for (int e = 0; e < 4; ++e) o[e] = f2bf(w1[e] + w4[e] * g[e]);
        *(u16x4*)(Wm + (size_t)b * 1048576 + (size_t)n * 1024 + k) = o;
    }
}

// ---------- unified async bf16 GEMM, C = A @ B^T, 128x128 tile, BK=64, swizzled LDS ----------
// (kept for MODE 0 and MODE 1; MODE 2 moved to gemm2_8ph below)
template<int MODE>
__global__ __launch_bounds__(256) void gemm_async(
    const u16* __restrict__ A0, const u16* __restrict__ A1, const u16* __restrict__ A2,
    const u16* __restrict__ B0, const u16* __restrict__ B1,
    float* __restrict__ of, u16* __restrict__ ob, const float* __restrict__ bias) {
    constexpr int NSEC = (MODE == 2) ? 3 : 1;
    constexpr int KSEC = (MODE == 1) ? 512 : 1024;
    constexpr int LDO  = (MODE == 0) ? 512 : 1024;
    constexpr int NTILES = (MODE == 0) ? 4 : 8;
    __shared__ u16 As[128 * 64];
    __shared__ u16 Bs[128 * 64];
    const int tid  = threadIdx.x;
    const int lane = tid & 63;
    const int wave = tid >> 6;
    const int lin  = blockIdx.x;
    const int b    = lin & 7;            // XCD pin
    const int rem  = lin >> 3;
    const int n0   = (rem % NTILES) * 128;
    const int m0   = (rem / NTILES) * 128;

    const u16* Aarr[NSEC];
    const u16* Barr[NSEC];
    int lda_[NSEC], ldb_[NSEC];
    if constexpr (MODE == 0) {
        Aarr[0] = A0 + (size_t)b * C_LEN * D_DIM; lda_[0] = 1024;
        Barr[0] = B0 + (size_t)b * Q_LEN * D_DIM; ldb_[0] = 1024;
    } else if constexpr (MODE == 1) {
        Aarr[0] = A0 + (size_t)b * C_LEN * Q_LEN; lda_[0] = 512;
        Barr[0] = B0 + (size_t)b * D_DIM * Q_LEN; ldb_[0] = 512;
    } else {
        Aarr[0] = A0 + (size_t)b * C_LEN * D_DIM;  lda_[0] = 1024;
        Barr[0] = B0 + (size_t)b * D_DIM * D_DIM;  ldb_[0] = 1024;   // Wm (per-batch)
        Aarr[1] = A1 + (size_t)b * C_LEN * 2048;        lda_[1] = 2048;  // CC + 0
        Barr[1] = B1;                                   ldb_[1] = 2048;  // Wbf + 0
        Aarr[2] = A1 + (size_t)b * C_LEN * 2048 + 1024; lda_[2] = 2048;  // CC + 1024
        Barr[2] = B1 + 1024;                            ldb_[2] = 2048;  // Wbf + 1024
    }

    // staging geometry: 16 chunks of 8 rows; wave w stages chunks 4w..4w+3
    const int srow = lane >> 3;                    // 0..7 row-within-chunk
    const int ssc  = ((lane & 7) ^ srow) * 8;      // swizzled source column (u16)

    floatx4 acc[4][4];
    #pragma unroll
    for (int i = 0; i < 4; ++i)
        #pragma unroll
        for (int j = 0; j < 4; ++j)
            acc[i][j] = (floatx4)(0.0f);

    const int wrow = (wave >> 1) * 64;
    const int wcol = (wave & 1) * 64;
    const int quad = lane >> 4;
    const int lrow = lane & 15;
    const int sw7  = lane & 7;                     // row&7 for all reader rows

    #pragma unroll
    for (int sec = 0; sec < NSEC; ++sec) {
        const u16* __restrict__ Ab = Aarr[sec];
        const u16* __restrict__ Bb = Barr[sec];
        const int LA = lda_[sec];
        const int LB = ldb_[sec];
        for (int k0 = 0; k0 < KSEC; k0 += 64) {
            #pragma unroll
            for (int cc = 0; cc < 4; ++cc) {
                int ch = wave * 4 + cc;
                int rr = ch * 8 + srow;
                async16(Ab + (size_t)(m0 + rr) * LA + k0 + ssc, &As[ch * 512]);
            }
            #pragma unroll
            for (int cc = 0; cc < 4; ++cc) {
                int ch = wave * 4 + cc;
                int rr = ch * 8 + srow;
                async16(Bb + (size_t)(n0 + rr) * LB + k0 + ssc, &Bs[ch * 512]);
            }
            __syncthreads();
            #pragma unroll
            for (int h = 0; h < 2; ++h) {
                const int pc = ((h * 4 + quad) ^ sw7) * 8;   // physical column (u16)
                bf16x8 af[4], bfr[4];
                #pragma unroll
                for (int i = 0; i < 4; ++i)
                    af[i] = __builtin_bit_cast(bf16x8, *(const short8*)&As[(wrow + i*16 + lrow) * 64 + pc]);
                #pragma unroll
                for (int j = 0; j < 4; ++j)
                    bfr[j] = __builtin_bit_cast(bf16x8, *(const short8*)&Bs[(wcol + j*16 + lrow) * 64 + pc]);
                #pragma unroll
                for (int i = 0; i < 4; ++i)
                    #pragma unroll
                    for (int j = 0; j < 4; ++j)
                        acc[i][j] = __builtin_amdgcn_mfma_f32_16x16x32_bf16(af[i], bfr[j], acc[i][j], 0, 0, 0);
            }
            __syncthreads();
        }
    }

    // ---- epilogue; C/D layout: col = lane&15, row = quad*4 + reg ----
    float* ofb = nullptr; u16* ccb = nullptr; const u16* cbr = nullptr;
    if (MODE == 0)      ofb = of + (size_t)b * C_LEN * Q_LEN;
    else if (MODE == 1) { ccb = ob + (size_t)b * C_LEN * 2048; cbr = A1 + (size_t)b * C_LEN * D_DIM; }
    else                ofb = of + (size_t)b * C_LEN * D_DIM;
    #pragma unroll
    for (int i = 0; i < 4; ++i) {
        #pragma unroll
        for (int j = 0; j < 4; ++j) {
            #pragma unroll
            for (int e = 0; e < 4; ++e) {
                int gm = m0 + wrow + i * 16 + quad * 4 + e;
                int gn = n0 + wcol + j * 16 + lrow;
                float v = acc[i][j][e];
                if (MODE == 0)      ofb[(size_t)gm * LDO + gn] = v;
                else if (MODE == 1) {
                    u16 p = f2bf(v);
                    float cv = bf2f(cbr[(size_t)gm * 1024 + gn]);
                    ccb[(size_t)gm * 2048 + gn]        = p;
                    ccb[(size_t)gm * 2048 + 1024 + gn] = f2bf(cv * bf2f(p));
                }
                else                ofb[(size_t)gm * LDO + gn] = v + bias[gn];
            }
        }
    }
}

// ---------- 256x256-tile, 8-phase, counted-vmcnt bf16 GEMM for the output projection ----------
// z[b] = cbf[b] @ Wm[b]^T + CC0[b] @ Wbf0^T + CC1[b] @ Wbf1^T + b_l   (K = 3*1024 = 48 tiles of 64)
//
// Schedule invariants (liveness-proven):
//   * LDS = 2 K-tile buffers x {A,B} x 2 K-halves; stage unit = one K-half of A or B
//     (256 rows x 32 cols, 16 KiB, 2 global_load_lds_dwordx4 per wave).
//   * Per K-tile t, 4 phases (m-half x k-half), 16 MFMA each. Unit last-read:
//     Bk0@p0, Ak0@p1, Bk32@p2, Ak32@p3. Stage issue slots (one phase after death):
//     p0: Ak32(t+1) | p1: Bk0(t+2) | p2: Ak0(t+2) | p3: Bk32(t+2).
//   * Readiness: s_waitcnt vmcnt(10) (= 5 units in flight) immediately BEFORE the
//     end barrier of p1 and p3 guarantees, in steady state, that the units read by
//     the next two phases have landed. Last 2 tiles fall back to vmcnt(0).
//   * Raw s_barrier (no implicit drain) + sched_barrier(0) pins adjacent to every
//     barrier/waitcnt so the compiler cannot move memory ops across the sync points.
#define PIN() __builtin_amdgcn_sched_barrier(0)
#define BAR8() do { PIN(); __builtin_amdgcn_s_barrier(); PIN(); } while (0)
#define VMW(N) do { asm volatile("s_waitcnt vmcnt(" #N ")" ::: "memory"); } while (0)

#define LDA4(DST, MQ, KH, CUR) do { \
    const u16* un_ = lds_ + (CUR) * 32768 + (KH) * 8192; \
    _Pragma("unroll") \
    for (int i_ = 0; i_ < 4; ++i_) \
      (DST)[i_] = __builtin_bit_cast(bf16x8, \
          *(const short8*)(un_ + (wm * 128 + (MQ) * 64 + i_ * 16 + lrow) * 32 + pcs)); \
  } while (0)

#define LDB4(DST, KH, CUR) do { \
    const u16* un_ = lds_ + (CUR) * 32768 + 16384 + (KH) * 8192; \
    _Pragma("unroll") \
    for (int i_ = 0; i_ < 4; ++i_) \
      (DST)[i_] = __builtin_bit_cast(bf16x8, \
          *(const short8*)(un_ + (wn * 64 + i_ * 16 + lrow) * 32 + pcs)); \
  } while (0)

#define MFMA16(MQ4, A_, B_) do { \
    __builtin_amdgcn_s_setprio(1); \
    _Pragma("unroll") \
    for (int i_ = 0; i_ < 4; ++i_) { \
      _Pragma("unroll") \
      for (int j_ = 0; j_ < 4; ++j_) \
        acc[(MQ4) + i_][j_] = __builtin_amdgcn_mfma_f32_16x16x32_bf16( \
            (A_)[i_], (B_)[j_], acc[(MQ4) + i_][j_], 0, 0, 0); \
    } \
    __builtin_amdgcn_s_setprio(0); \
  } while (0)

__global__ __launch_bounds__(512, 2) void gemm2_8ph(
    const u16* __restrict__ cbf, const u16* __restrict__ CC,
    const u16* __restrict__ Wm, const u16* __restrict__ Wbf,
    float* __restrict__ of, const float* __restrict__ bias) {
    __shared__ __align__(16) u16 lds_[65536];  // [buf2][A|B][kh2][row256][col32] = 128 KiB
    const int tid  = threadIdx.x;
    const int lane = tid & 63;
    const int wave = tid >> 6;          // 8 waves: 2 (M) x 4 (N)
    const int lin  = blockIdx.x;
    const int b    = lin & 7;           // XCD pin: one batch per XCD
    const int rem  = lin >> 3;          // 0..31 -> 8 m-tiles x 4 n-tiles
    const int n0   = (rem & 3) * 256;
    const int m0   = (rem >> 2) * 256;
    const int wm   = wave >> 2;         // 0..1  -> rows m0+wm*128 .. +127
    const int wn   = wave & 3;          // 0..3  -> cols n0+wn*64 .. +63
    const int quad = lane >> 4;
    const int lrow = lane & 15;
    const int pcs  = (quad ^ (lrow & 3)) * 8;   // swizzled 16B chunk within k-half

    const u16* Acb  = cbf + (size_t)b * (C_LEN * D_DIM);
    const u16* Acc0 = CC  + (size_t)b * (C_LEN * 2048);
    const u16* Acc1 = Acc0 + 1024;
    const u16* Bwm  = Wm  + (size_t)b * (D_DIM * D_DIM);

    // stage one K-half unit (ab: 0=A,1=B) of tile tt into LDS buffer tt&1.
    // linear LDS dest (wave-uniform base; HW adds lane*16), inverse-swizzled source.
    auto STAGE = [&](int tt, int ab, int kh) {
        const int sec = tt >> 4;                    // 3 K-sections of 16 tiles
        const int kl  = (tt & 15) * 64 + kh * 32;   // local k within section
        const u16* base;
        int r0;
        if (ab == 0) { base = (sec == 0) ? Acb : (sec == 1) ? Acc0 : Acc1; r0 = m0; }
        else         { base = (sec == 0) ? Bwm : (sec == 1) ? Wbf  : Wbf + 1024; r0 = n0; }
        const int ld = (sec == 0) ? 1024 : 2048;
        u16* unit = lds_ + (tt & 1) * 32768 + ab * 16384 + kh * 8192;
        #pragma unroll
        for (int l = 0; l < 2; ++l) {
            const int li  = l * 512 + tid;          // 0..1023 -> (row, chunk)
            const int row = li >> 2;
            const int sc  = (li & 3) ^ (row & 3);   // inverse swizzle on global col
            async16(base + (size_t)(r0 + row) * ld + kl + sc * 8,
                    unit + (l * 512 + (tid & ~63)) * 8);
        }
    };

    floatx4 acc[8][4];
    #pragma unroll
    for (int i = 0; i < 8; ++i)
        #pragma unroll
        for (int j = 0; j < 4; ++j) acc[i][j] = (floatx4)(0.0f);

    // prologue: all units of tiles 0,1 except Ak32(1) (issued at (0,p0)).
    STAGE(0, 1, 0); PIN(); STAGE(0, 0, 0); PIN(); STAGE(0, 1, 1); PIN(); STAGE(0, 0, 1); PIN();
    STAGE(1, 1, 0); PIN(); STAGE(1, 0, 0); PIN(); STAGE(1, 1, 1); PIN();
    VMW(10);                       // oldest 2 units (Bk0(0), Ak0(0)) landed
    BAR8();

    bf16x8 af[4], bf[4];
    for (int tt = 0; tt < 48; ++tt) {
        const int cur = tt & 1;
        // ---- p0: acc rows 0-3, k 0-31 (reads Ak0(t), Bk0(t)) ----
        if (tt + 1 < 48) STAGE(tt + 1, 0, 1);     // Ak32(t+1): dead since (t-1,p3)
        LDA4(af, 0, 0, cur);
        LDB4(bf, 0, cur);
        BAR8();
        MFMA16(0, af, bf);
        BAR8();
        // ---- p1: acc rows 4-7, k 0-31 (B frags reused from regs) ----
        if (tt + 2 < 48) STAGE(tt + 2, 1, 0);     // Bk0(t+2): dead since p0
        LDA4(af, 1, 0, cur);
        BAR8();
        MFMA16(4, af, bf);
        if (tt < 46) VMW(10); else VMW(0);        // guards p2's Bk32(t), Ak32(t)
        BAR8();
        // ---- p2: acc rows 0-3, k 32-63 ----
        if (tt + 2 < 48) STAGE(tt + 2, 0, 0);     // Ak0(t+2): dead since p1
        LDA4(af, 0, 1, cur);
        LDB4(bf, 1, cur);
        BAR8();
        MFMA16(0, af, bf);
        BAR8();
        // ---- p3: acc rows 4-7, k 32-63 ----
        if (tt + 2 < 48) STAGE(tt + 2, 1, 1);     // Bk32(t+2): dead since p2
        LDA4(af, 1, 1, cur);
        BAR8();
        MFMA16(4, af, bf);
        if (tt < 46) VMW(10); else VMW(0);        // guards (t+1,p0)'s Bk0, Ak0
        BAR8();
    }

    // ---- epilogue; C/D layout: col = lane&15, row = quad*4 + reg ----
    float bs[4];
    #pragma unroll
    for (int j = 0; j < 4; ++j) bs[j] = bias[n0 + wn * 64 + j * 16 + lrow];
    float* ofb = of + (size_t)b * (C_LEN * D_DIM);
    #pragma unroll
    for (int i = 0; i < 8; ++i) {
        #pragma unroll
        for (int j = 0; j < 4; ++j) {
            #pragma unroll
            for (int e = 0; e < 4; ++e) {
                const int gm = m0 + wm * 128 + i * 16 + quad * 4 + e;
                const int gn = n0 + wn * 64 + j * 16 + lrow;
                ofb[(size_t)gm * D_DIM + gn] = acc[i][j][e] + bs[j];
            }
        }
    }
}

// ---------- softmax over Q per (b,c) row; also record rowmax ----------
__global__ void softmax_kernel(const float* __restrict__ S, const float* __restrict__ colterm,
                               u16* __restrict__ P, float* __restrict__ mbuf) {
    int row = blockIdx.x * 4 + (threadIdx.x >> 6);
    int lane = threadIdx.x & 63;
    int b = row >> 11;  // C_LEN = 2048
    const float* sp = S + (size_t)row * Q_LEN;
    const float* cp = colterm + (size_t)b * Q_LEN;
    float v[8];
    float m = -1e30f;
    #pragma unroll
    for (int j = 0; j < 8; ++j) {
        int idx = j * 64 + lane;
        v[j] = sp[idx] + cp[idx];
        m = fmaxf(m, v[j]);
    }
    for (int off = 32; off; off >>= 1) m = fmaxf(m, __shfl_xor(m, off));
    float s = 0.f;
    #pragma unroll
    for (int j = 0; j < 8; ++j) { v[j] = __expf(v[j] - m); s += v[j]; }
    for (int off = 32; off; off >>= 1) s += __shfl_xor(s, off);
    float inv = 1.0f / s;
    u16* pp = P + (size_t)row * Q_LEN;
    #pragma unroll
    for (int j = 0; j < 8; ++j) pp[j * 64 + lane] = f2bf(v[j] * inv);
    if (lane == 0) mbuf[row] = m;
}

// ---------- b_att[b,c] = softmax_c(rowmax + rowterm) ----------
__global__ __launch_bounds__(256) void batt_kernel(const float* __restrict__ mbuf,
                                                   const float* __restrict__ rowterm,
                                                   float* __restrict__ batt) {
    __shared__ float red[8];
    int b = blockIdx.x;
    int tid = threadIdx.x;
    const float* mb = mbuf + (size_t)b * C_LEN;
    const float* rt = rowterm + (size_t)b * C_LEN;
    float v[8];
    float m = -1e30f;
    #pragma unroll
    for (int j = 0; j < 8; ++j) { int idx = j * 256 + tid; v[j] = mb[idx] + rt[idx]; m = fmaxf(m, v[j]); }
    for (int off = 32; off; off >>= 1) m = fmaxf(m, __shfl_xor(m, off));
    int wave = tid >> 6, lane = tid & 63;
    if (lane == 0) red[wave] = m;
    __syncthreads();
    m = fmaxf(fmaxf(red[0], red[1]), fmaxf(red[2], red[3]));
    float s = 0.f;
    #pragma unroll
    for (int j = 0; j < 8; ++j) { v[j] = __expf(v[j] - m); s += v[j]; }
    for (int off = 32; off; off >>= 1) s += __shfl_xor(s, off);
    if (lane == 0) red[4 + wave] = s;
    __syncthreads();
    s = red[4] + red[5] + red[6] + red[7];
    float inv = 1.0f / s;
    float* bb = batt + (size_t)b * C_LEN;
    #pragma unroll
    for (int j = 0; j < 8; ++j) bb[j * 256 + tid] = v[j] * inv;
}

// ---------- q2c[b,d] = sum_c b_att[b,c] * cbf[b,c,d] (chunked + atomic) ----------
__global__ __launch_bounds__(256) void q2c_kernel(const float* __restrict__ batt,
                                                  const u16* __restrict__ cbf,
                                                  float* __restrict__ q2c) {
    int d  = blockIdx.x * 256 + threadIdx.x;
    int b  = blockIdx.y;
    int c0 = blockIdx.z * 256;
    const u16* cb = cbf + ((size_t)b * C_LEN + c0) * D_DIM + d;
    const float* bb = batt + (size_t)b * C_LEN + c0;
    float s = 0.f;
    #pragma unroll 4
    for (int i = 0; i < 256; ++i) s += bb[i] * bf2f(cb[(size_t)i * D_DIM]);
    atomicAdd(&q2c[(size_t)b * D_DIM + d], s);
}

extern "C" void kernel_launch(void* const* d_in, const int* in_sizes, int n_in,
                              void* d_out, int out_size, void* d_ws, size_t ws_size,
                              hipStream_t stream) {
    const float* c   = (const float*)d_in[0];
    const float* q   = (const float*)d_in[1];
    const float* wcq = (const float*)d_in[2];
    // b_cq (d_in[3]), b_c (d_in[5]), b_q (d_in[7]) cancel in both softmaxes — unused.
    const float* w_c = (const float*)d_in[4];
    const float* w_q = (const float*)d_in[6];
    const float* W_l = (const float*)d_in[8];
    const float* b_l = (const float*)d_in[9];
    float* out = (float*)d_out;

    char* ws = (char*)d_ws;
    // Region plan (MiB), lifetime-safe re-use:
    //   [0,32)    cbf                       (prep .. gemm2)
    //   [32,96)   CC interleaved c2q|cc2q   (written gemm<1>, read gemm2)
    //             before gemm<1>: S fp32 @32..64, qwbf @64..72
    //   [96,112)  P bf16 (softmax..gemm<1>), then Wm (wmerge_all..gemm2)
    //   [112,120) qT (prep..gemm<1>), then Wbf compact 4MiB (wmerge_all..gemm2)
    //   [120,...) smalls
    u16*   cbf     = (u16*)ws;
    float* S       = (float*)(ws + 33554432);
    u16*   CC      = (u16*)(ws + 33554432);
    u16*   qwbf    = (u16*)(ws + 67108864);
    u16*   P       = (u16*)(ws + 100663296);
    u16*   Wm      = (u16*)(ws + 100663296);
    u16*   qT      = (u16*)(ws + 117440512);
    u16*   Wbf     = (u16*)(ws + 117440512);
    float* rowterm = (float*)(ws + 125829120);
    float* colterm = (float*)(ws + 125894656);
    float* mbuf    = (float*)(ws + 125911040);
    float* batt    = (float*)(ws + 125976576);
    float* q2c     = (float*)(ws + 126042112);   // total ~120.3 MiB

    prep_kernel<<<dim3(9248), dim3(256), 0, stream>>>(c, q, wcq, w_c, w_q,
                                                      cbf, qwbf, qT, rowterm, colterm, q2c);
    gemm_async<0><<<dim3(512), dim3(256), 0, stream>>>(cbf, nullptr, nullptr, qwbf, nullptr, S, nullptr, nullptr);
    softmax_kernel<<<dim3(4096), dim3(256), 0, stream>>>(S, colterm, P, mbuf);
    batt_kernel<<<dim3(8), dim3(256), 0, stream>>>(mbuf, rowterm, batt);
    q2c_kernel<<<dim3(4, 8, 8), dim3(256), 0, stream>>>(batt, cbf, q2c);
    gemm_async<1><<<dim3(1024), dim3(256), 0, stream>>>(P, cbf, nullptr, qT, nullptr, nullptr, CC, nullptr);
    wmerge_all<<<dim3(1024), dim3(256), 0, stream>>>(W_l, q2c, Wm, Wbf);
    gemm2_8ph<<<dim3(256), dim3(512), 0, stream>>>(cbf, CC, Wm, Wbf, out, b_l);
}

// Round 3
// 348.887 us; speedup vs baseline: 1.0424x; 1.0262x over previous
//
#include <hip/hip_runtime.h>

typedef unsigned short u16;
typedef __attribute__((ext_vector_type(4))) float floatx4;
typedef __attribute__((ext_vector_type(4))) unsigned short u16x4;
typedef __attribute__((ext_vector_type(8))) short short8;
typedef __attribute__((ext_vector_type(8))) __bf16 bf16x8;

#define B_SZ 8
#define C_LEN 2048
#define Q_LEN 512
#define D_DIM 1024
#define K4 (4 * D_DIM)

static __device__ __forceinline__ u16 f2bf(float f) {
    union { float f; unsigned int u; } v; v.f = f;
    unsigned int r = v.u + 0x7FFFu + ((v.u >> 16) & 1u);  // round-to-nearest-even
    return (u16)(r >> 16);
}
static __device__ __forceinline__ float bf2f(u16 h) {
    union { unsigned int u; float f; } v; v.u = ((unsigned int)h) << 16;
    return v.f;
}

// async global->LDS, 16B per lane; LDS dest = wave-uniform base + lane*16
static __device__ __forceinline__ void async16(const void* g, void* l) {
    __builtin_amdgcn_global_load_lds(
        (const __attribute__((address_space(1))) unsigned int*)g,
        (__attribute__((address_space(3))) unsigned int*)(unsigned int)(unsigned long long)l,
        16, 0, 0);
}

// ---------- fused prep: precast_c | precast_q | transpose_q | zero q2c ----------
__global__ __launch_bounds__(256) void prep_kernel(
    const float* __restrict__ c, const float* __restrict__ q,
    const float* __restrict__ w_cq, const float* __restrict__ w_c, const float* __restrict__ w_q,
    u16* __restrict__ cbf, u16* __restrict__ qwbf, u16* __restrict__ qT,
    float* __restrict__ rowterm, float* __restrict__ colterm, float* __restrict__ q2c) {
    int blk = blockIdx.x;
    int tid = threadIdx.x;
    if (blk < 4096) {
        // precast_c: cbf = bf16(c); rowterm = c . w_c
        int row = blk * 4 + (tid >> 6);
        int lane = tid & 63;
        const float* src = c + (size_t)row * D_DIM;
        u16* dst = cbf + (size_t)row * D_DIM;
        float s = 0.f;
        #pragma unroll
        for (int j = 0; j < 4; ++j) {
            int idx = j * 256 + lane * 4;
            floatx4 a = *(const floatx4*)(src + idx);
            floatx4 w = *(const floatx4*)(w_c + idx);
            s += a[0]*w[0] + a[1]*w[1] + a[2]*w[2] + a[3]*w[3];
            u16x4 o;
            #pragma unroll
            for (int e = 0; e < 4; ++e) o[e] = f2bf(a[e]);
            *(u16x4*)(dst + idx) = o;
        }
        for (int off = 32; off; off >>= 1) s += __shfl_down(s, off);
        if (lane == 0) rowterm[row] = s;
    } else if (blk < 5120) {
        // precast_q: qwbf = bf16(q .* w_cq); colterm = q . w_q
        int row = (blk - 4096) * 4 + (tid >> 6);
        int lane = tid & 63;
        const float* src = q + (size_t)row * D_DIM;
        u16* dst = qwbf + (size_t)row * D_DIM;
        float s = 0.f;
        #pragma unroll
        for (int j = 0; j < 4; ++j) {
            int idx = j * 256 + lane * 4;
            floatx4 a  = *(const floatx4*)(src + idx);
            floatx4 wc = *(const floatx4*)(w_cq + idx);
            floatx4 wq = *(const floatx4*)(w_q + idx);
            s += a[0]*wq[0] + a[1]*wq[1] + a[2]*wq[2] + a[3]*wq[3];
            u16x4 o;
            #pragma unroll
            for (int e = 0; e < 4; ++e) o[e] = f2bf(a[e] * wc[e]);
            *(u16x4*)(dst + idx) = o;
        }
        for (int off = 32; off; off >>= 1) s += __shfl_down(s, off);
        if (lane == 0) colterm[row] = s;
    } else if (blk < 9216) {
        // transpose_q: qT[b,d,q] = bf16(q[b,q,d])
        __shared__ float tile[32][33];
        int t = blk - 5120;
        int q0 = (t & 15) * 32;
        int d0 = ((t >> 4) & 31) * 32;
        int b = t >> 9;
        int tx = tid & 31, ty = tid >> 5;  // 32 x 8
        const float* qb = q + (size_t)b * Q_LEN * D_DIM;
        #pragma unroll
        for (int j = 0; j < 4; ++j) {
            int row = ty + j * 8;
            tile[row][tx] = qb[(size_t)(q0 + row) * D_DIM + d0 + tx];
        }
        __syncthreads();
        u16* qTb = qT + (size_t)b * D_DIM * Q_LEN;
        #pragma unroll
        for (int j = 0; j < 4; ++j) {
            int row = ty + j * 8;
            qTb[(size_t)(d0 + row) * Q_LEN + q0 + tx] = f2bf(tile[tx][row]);
        }
    } else {
        // zero q2c (8192 floats)
        int i = (blk - 9216) * 256 + tid;
        q2c[i] = 0.0f;
    }
}

// ---------- fused W prep: Wm[b,n,k] = bf16(W1 + W4*q2c); Wbf[n,kk] = bf16(W[n,1024+kk]) ----------
__global__ __launch_bounds__(256) void wmerge_all(const float* __restrict__ W, const float* __restrict__ q2c,
                                                  u16* __restrict__ Wm, u16* __restrict__ Wbf) {
    int n = blockIdx.x;             // 1024 rows
    int k = threadIdx.x * 4;        // 0..1023
    const float* wr = W + (size_t)n * K4;
    floatx4 w1 = *(const floatx4*)(wr + k);
    floatx4 w4 = *(const floatx4*)(wr + 3072 + k);
    #pragma unroll
    for (int p = 0; p < 2; ++p) {
        int kk = p * 1024 + k;
        floatx4 v = *(const floatx4*)(wr + 1024 + kk);
        u16x4 o;
        #pragma unroll
        for (int e = 0; e < 4; ++e) o[e] = f2bf(v[e]);
        *(u16x4*)(Wbf + (size_t)n * 2048 + kk) = o;
    }
    #pragma unroll
    for (int b = 0; b < 8; ++b) {
        floatx4 g = *(const floatx4*)(q2c + (size_t)b * D_DIM + k);
        u16x4 o;
        #pragma unroll
        for (int e = 0; e < 4; ++e) o[e] = f2bf(w1[e] + w4[e] * g[e]);
        *(u16x4*)(Wm + (size_t)b * 1048576 + (size_t)n * 1024 + k) = o;
    }
}

// ---------- unified async bf16 GEMM, C = A @ B^T, 128x128 tile, BK=64, swizzled LDS ----------
// (kept for MODE 0 and MODE 1; MODE 2 uses gemm2_8ph below)
template<int MODE>
__global__ __launch_bounds__(256) void gemm_async(
    const u16* __restrict__ A0, const u16* __restrict__ A1, const u16* __restrict__ A2,
    const u16* __restrict__ B0, const u16* __restrict__ B1,
    float* __restrict__ of, u16* __restrict__ ob, const float* __restrict__ bias) {
    constexpr int NSEC = (MODE == 2) ? 3 : 1;
    constexpr int KSEC = (MODE == 1) ? 512 : 1024;
    constexpr int LDO  = (MODE == 0) ? 512 : 1024;
    constexpr int NTILES = (MODE == 0) ? 4 : 8;
    __shared__ u16 As[128 * 64];
    __shared__ u16 Bs[128 * 64];
    const int tid  = threadIdx.x;
    const int lane = tid & 63;
    const int wave = tid >> 6;
    const int lin  = blockIdx.x;
    const int b    = lin & 7;            // XCD pin
    const int rem  = lin >> 3;
    const int n0   = (rem % NTILES) * 128;
    const int m0   = (rem / NTILES) * 128;

    const u16* Aarr[NSEC];
    const u16* Barr[NSEC];
    int lda_[NSEC], ldb_[NSEC];
    if constexpr (MODE == 0) {
        Aarr[0] = A0 + (size_t)b * C_LEN * D_DIM; lda_[0] = 1024;
        Barr[0] = B0 + (size_t)b * Q_LEN * D_DIM; ldb_[0] = 1024;
    } else if constexpr (MODE == 1) {
        Aarr[0] = A0 + (size_t)b * C_LEN * Q_LEN; lda_[0] = 512;
        Barr[0] = B0 + (size_t)b * D_DIM * Q_LEN; ldb_[0] = 512;
    } else {
        Aarr[0] = A0 + (size_t)b * C_LEN * D_DIM;  lda_[0] = 1024;
        Barr[0] = B0 + (size_t)b * D_DIM * D_DIM;  ldb_[0] = 1024;   // Wm (per-batch)
        Aarr[1] = A1 + (size_t)b * C_LEN * 2048;        lda_[1] = 2048;  // CC + 0
        Barr[1] = B1;                                   ldb_[1] = 2048;  // Wbf + 0
        Aarr[2] = A1 + (size_t)b * C_LEN * 2048 + 1024; lda_[2] = 2048;  // CC + 1024
        Barr[2] = B1 + 1024;                            ldb_[2] = 2048;  // Wbf + 1024
    }

    // staging geometry: 16 chunks of 8 rows; wave w stages chunks 4w..4w+3
    const int srow = lane >> 3;                    // 0..7 row-within-chunk
    const int ssc  = ((lane & 7) ^ srow) * 8;      // swizzled source column (u16)

    floatx4 acc[4][4];
    #pragma unroll
    for (int i = 0; i < 4; ++i)
        #pragma unroll
        for (int j = 0; j < 4; ++j)
            acc[i][j] = (floatx4)(0.0f);

    const int wrow = (wave >> 1) * 64;
    const int wcol = (wave & 1) * 64;
    const int quad = lane >> 4;
    const int lrow = lane & 15;
    const int sw7  = lane & 7;                     // row&7 for all reader rows

    #pragma unroll
    for (int sec = 0; sec < NSEC; ++sec) {
        const u16* __restrict__ Ab = Aarr[sec];
        const u16* __restrict__ Bb = Barr[sec];
        const int LA = lda_[sec];
        const int LB = ldb_[sec];
        for (int k0 = 0; k0 < KSEC; k0 += 64) {
            #pragma unroll
            for (int cc = 0; cc < 4; ++cc) {
                int ch = wave * 4 + cc;
                int rr = ch * 8 + srow;
                async16(Ab + (size_t)(m0 + rr) * LA + k0 + ssc, &As[ch * 512]);
            }
            #pragma unroll
            for (int cc = 0; cc < 4; ++cc) {
                int ch = wave * 4 + cc;
                int rr = ch * 8 + srow;
                async16(Bb + (size_t)(n0 + rr) * LB + k0 + ssc, &Bs[ch * 512]);
            }
            __syncthreads();
            #pragma unroll
            for (int h = 0; h < 2; ++h) {
                const int pc = ((h * 4 + quad) ^ sw7) * 8;   // physical column (u16)
                bf16x8 af[4], bfr[4];
                #pragma unroll
                for (int i = 0; i < 4; ++i)
                    af[i] = __builtin_bit_cast(bf16x8, *(const short8*)&As[(wrow + i*16 + lrow) * 64 + pc]);
                #pragma unroll
                for (int j = 0; j < 4; ++j)
                    bfr[j] = __builtin_bit_cast(bf16x8, *(const short8*)&Bs[(wcol + j*16 + lrow) * 64 + pc]);
                #pragma unroll
                for (int i = 0; i < 4; ++i)
                    #pragma unroll
                    for (int j = 0; j < 4; ++j)
                        acc[i][j] = __builtin_amdgcn_mfma_f32_16x16x32_bf16(af[i], bfr[j], acc[i][j], 0, 0, 0);
            }
            __syncthreads();
        }
    }

    // ---- epilogue; C/D layout: col = lane&15, row = quad*4 + reg ----
    float* ofb = nullptr; u16* ccb = nullptr; const u16* cbr = nullptr;
    if (MODE == 0)      ofb = of + (size_t)b * C_LEN * Q_LEN;
    else if (MODE == 1) { ccb = ob + (size_t)b * C_LEN * 2048; cbr = A1 + (size_t)b * C_LEN * D_DIM; }
    else                ofb = of + (size_t)b * C_LEN * D_DIM;
    #pragma unroll
    for (int i = 0; i < 4; ++i) {
        #pragma unroll
        for (int j = 0; j < 4; ++j) {
            #pragma unroll
            for (int e = 0; e < 4; ++e) {
                int gm = m0 + wrow + i * 16 + quad * 4 + e;
                int gn = n0 + wcol + j * 16 + lrow;
                float v = acc[i][j][e];
                if (MODE == 0)      ofb[(size_t)gm * LDO + gn] = v;
                else if (MODE == 1) {
                    u16 p = f2bf(v);
                    float cv = bf2f(cbr[(size_t)gm * 1024 + gn]);
                    ccb[(size_t)gm * 2048 + gn]        = p;
                    ccb[(size_t)gm * 2048 + 1024 + gn] = f2bf(cv * bf2f(p));
                }
                else                ofb[(size_t)gm * LDO + gn] = v + bias[gn];
            }
        }
    }
}

// ---------- 256x256-tile, 4-phase, counted-vmcnt bf16 GEMM for the output projection ----------
// z[b] = cbf[b] @ Wm[b]^T + CC0[b] @ Wbf0^T + CC1[b] @ Wbf1^T + b_l   (K = 3*1024 = 48 tiles of 64)
//
// LDS units are full-BK [256 rows][64 k] (128B row stride) with the PROVEN 8-chunk
// XOR swizzle (phys_chunk = logical ^ (row&7); row&7 == lane&7 for all fragment
// reads) — the round-0 [256][32] 64B-row geometry caused a uniform +4cyc/ds_read
// bank conflict (9.4M/dispatch).
//
// Liveness (full-K units, 2 buffers):
//   * A(t) last read @p3, B(t) last read @p2 (p3 reuses B frags from registers).
//   * Reads of unit X are DRAINED chip-wide at the end-of-phase barrier of X's
//     last-read phase (each wave's MFMA forces lgkmcnt on its own reads).
//   * Stage slots: A(t+1) @p0(t) (opposite buffer, A(t-1) drained at p3(t-1) end);
//                  B(t+2) @p3(t) (same buffer, B(t) drained at p2(t) end).
//   * vmcnt(4) at p3(t) end leaves only B(t+2) in flight => A(t+1), B(t+1) landed
//     before tile t+1. Never drains to 0 in steady state; tail (tt>=46) drains.
#define PIN() __builtin_amdgcn_sched_barrier(0)
#define BAR8() do { PIN(); __builtin_amdgcn_s_barrier(); PIN(); } while (0)
#define VMW(N) do { asm volatile("s_waitcnt vmcnt(" #N ")" ::: "memory"); } while (0)

#define LDA4(DST, MQ, KH, CUR) do { \
    const u16* un_ = lds_ + (CUR) * 32768; \
    _Pragma("unroll") \
    for (int i_ = 0; i_ < 4; ++i_) \
      (DST)[i_] = __builtin_bit_cast(bf16x8, \
          *(const short8*)(un_ + (wm * 128 + (MQ) * 64 + i_ * 16 + lrow) * 64 + pca[KH])); \
  } while (0)

#define LDB4(DST, KH, CUR) do { \
    const u16* un_ = lds_ + (CUR) * 32768 + 16384; \
    _Pragma("unroll") \
    for (int i_ = 0; i_ < 4; ++i_) \
      (DST)[i_] = __builtin_bit_cast(bf16x8, \
          *(const short8*)(un_ + (wn * 64 + i_ * 16 + lrow) * 64 + pca[KH])); \
  } while (0)

#define MFMA16(MQ4, A_, B_) do { \
    __builtin_amdgcn_s_setprio(1); \
    _Pragma("unroll") \
    for (int i_ = 0; i_ < 4; ++i_) { \
      _Pragma("unroll") \
      for (int j_ = 0; j_ < 4; ++j_) \
        acc[(MQ4) + i_][j_] = __builtin_amdgcn_mfma_f32_16x16x32_bf16( \
            (A_)[i_], (B_)[j_], acc[(MQ4) + i_][j_], 0, 0, 0); \
    } \
    __builtin_amdgcn_s_setprio(0); \
  } while (0)

__global__ __launch_bounds__(512, 2) void gemm2_8ph(
    const u16* __restrict__ cbf, const u16* __restrict__ CC,
    const u16* __restrict__ Wm, const u16* __restrict__ Wbf,
    float* __restrict__ of, const float* __restrict__ bias) {
    __shared__ __align__(16) u16 lds_[65536];  // [buf2][A|B][row256][col64] = 128 KiB
    const int tid  = threadIdx.x;
    const int lane = tid & 63;
    const int wave = tid >> 6;          // 8 waves: 2 (M) x 4 (N)
    const int lin  = blockIdx.x;
    const int b    = lin & 7;           // XCD pin: one batch per XCD
    const int rem  = lin >> 3;          // 0..31 -> 8 m-tiles x 4 n-tiles
    const int n0   = (rem & 3) * 256;
    const int m0   = (rem >> 2) * 256;
    const int wm   = wave >> 2;         // 0..1  -> rows m0+wm*128 .. +127
    const int wn   = wave & 3;          // 0..3  -> cols n0+wn*64 .. +63
    const int quad = lane >> 4;
    const int lrow = lane & 15;
    const int lr7  = lane & 7;          // == row&7 for every fragment-read row
    // physical 16B chunk (u16 offset) for logical k-chunk (KH*4 + quad):
    const int pca[2] = { ((0 + quad) ^ lr7) * 8, ((4 + quad) ^ lr7) * 8 };

    const u16* Acb  = cbf + (size_t)b * (C_LEN * D_DIM);
    const u16* Acc0 = CC  + (size_t)b * (C_LEN * 2048);
    const u16* Acc1 = Acc0 + 1024;
    const u16* Bwm  = Wm  + (size_t)b * (D_DIM * D_DIM);

    // stage a full [256][64] unit (ab: 0=A,1=B) of tile tt into LDS buffer tt&1.
    // linear LDS dest (wave-uniform base; HW adds lane*16), inverse-swizzled source:
    // LDS[row][pchunk] = global[row][pchunk ^ (row&7)]  (8 chunks of 16B per row).
    auto STAGE = [&](int tt, int ab) {
        const int sec = tt >> 4;                    // 3 K-sections of 16 tiles
        const int kl  = (tt & 15) * 64;             // local k within section
        const u16* base;
        int r0;
        if (ab == 0) { base = (sec == 0) ? Acb : (sec == 1) ? Acc0 : Acc1; r0 = m0; }
        else         { base = (sec == 0) ? Bwm : (sec == 1) ? Wbf  : Wbf + 1024; r0 = n0; }
        const int ld = (sec == 0) ? 1024 : 2048;
        u16* unit = lds_ + (tt & 1) * 32768 + ab * 16384;
        #pragma unroll
        for (int l = 0; l < 4; ++l) {
            const int li  = l * 512 + tid;          // 0..2047 -> (row, chunk)
            const int row = li >> 3;
            const int sc  = (li & 7) ^ (row & 7);   // inverse swizzle on global col
            async16(base + (size_t)(r0 + row) * ld + kl + sc * 8,
                    unit + (size_t)(l * 512 + (tid & ~63)) * 8);
        }
    };

    floatx4 acc[8][4];
    #pragma unroll
    for (int i = 0; i < 8; ++i)
        #pragma unroll
        for (int j = 0; j < 4; ++j) acc[i][j] = (floatx4)(0.0f);

    // prologue: A(0), B(0), B(1); A(1) is staged at p0(0).
    STAGE(0, 0); PIN(); STAGE(0, 1); PIN(); STAGE(1, 1); PIN();
    VMW(4);                        // A(0), B(0) landed; B(1) in flight
    BAR8();

    bf16x8 af[4], bf[4];
    for (int tt = 0; tt < 48; ++tt) {
        const int cur = tt & 1;
        // ---- p0: acc rows 0-3, kh0 ----
        if (tt + 1 < 48) STAGE(tt + 1, 0);        // A(t+1) -> opposite buffer
        LDA4(af, 0, 0, cur);
        LDB4(bf, 0, cur);
        BAR8();
        MFMA16(0, af, bf);
        BAR8();
        // ---- p1: acc rows 4-7, kh0 (B frags reused from regs) ----
        LDA4(af, 1, 0, cur);
        BAR8();
        MFMA16(4, af, bf);
        BAR8();
        // ---- p2: acc rows 0-3, kh1 (last read of B(t)) ----
        LDA4(af, 0, 1, cur);
        LDB4(bf, 1, cur);
        BAR8();
        MFMA16(0, af, bf);
        BAR8();
        // ---- p3: acc rows 4-7, kh1 (last read of A(t)) ----
        if (tt + 2 < 48) STAGE(tt + 2, 1);        // B(t+2) -> same buffer (B(t) drained)
        LDA4(af, 1, 1, cur);
        BAR8();
        MFMA16(4, af, bf);
        if (tt < 46) { VMW(4); } else { VMW(0); } // leave only B(t+2) in flight
        BAR8();
    }

    // ---- epilogue; C/D layout: col = lane&15, row = quad*4 + reg ----
    float bs[4];
    #pragma unroll
    for (int j = 0; j < 4; ++j) bs[j] = bias[n0 + wn * 64 + j * 16 + lrow];
    float* ofb = of + (size_t)b * (C_LEN * D_DIM);
    #pragma unroll
    for (int i = 0; i < 8; ++i) {
        #pragma unroll
        for (int j = 0; j < 4; ++j) {
            #pragma unroll
            for (int e = 0; e < 4; ++e) {
                const int gm = m0 + wm * 128 + i * 16 + quad * 4 + e;
                const int gn = n0 + wn * 64 + j * 16 + lrow;
                ofb[(size_t)gm * D_DIM + gn] = acc[i][j][e] + bs[j];
            }
        }
    }
}

// ---------- softmax over Q per (b,c) row; also record rowmax ----------
__global__ void softmax_kernel(const float* __restrict__ S, const float* __restrict__ colterm,
                               u16* __restrict__ P, float* __restrict__ mbuf) {
    int row = blockIdx.x * 4 + (threadIdx.x >> 6);
    int lane = threadIdx.x & 63;
    int b = row >> 11;  // C_LEN = 2048
    const float* sp = S + (size_t)row * Q_LEN;
    const float* cp = colterm + (size_t)b * Q_LEN;
    float v[8];
    float m = -1e30f;
    #pragma unroll
    for (int j = 0; j < 8; ++j) {
        int idx = j * 64 + lane;
        v[j] = sp[idx] + cp[idx];
        m = fmaxf(m, v[j]);
    }
    for (int off = 32; off; off >>= 1) m = fmaxf(m, __shfl_xor(m, off));
    float s = 0.f;
    #pragma unroll
    for (int j = 0; j < 8; ++j) { v[j] = __expf(v[j] - m); s += v[j]; }
    for (int off = 32; off; off >>= 1) s += __shfl_xor(s, off);
    float inv = 1.0f / s;
    u16* pp = P + (size_t)row * Q_LEN;
    #pragma unroll
    for (int j = 0; j < 8; ++j) pp[j * 64 + lane] = f2bf(v[j] * inv);
    if (lane == 0) mbuf[row] = m;
}

// ---------- b_att[b,c] = softmax_c(rowmax + rowterm) ----------
__global__ __launch_bounds__(256) void batt_kernel(const float* __restrict__ mbuf,
                                                   const float* __restrict__ rowterm,
                                                   float* __restrict__ batt) {
    __shared__ float red[8];
    int b = blockIdx.x;
    int tid = threadIdx.x;
    const float* mb = mbuf + (size_t)b * C_LEN;
    const float* rt = rowterm + (size_t)b * C_LEN;
    float v[8];
    float m = -1e30f;
    #pragma unroll
    for (int j = 0; j < 8; ++j) { int idx = j * 256 + tid; v[j] = mb[idx] + rt[idx]; m = fmaxf(m, v[j]); }
    for (int off = 32; off; off >>= 1) m = fmaxf(m, __shfl_xor(m, off));
    int wave = tid >> 6, lane = tid & 63;
    if (lane == 0) red[wave] = m;
    __syncthreads();
    m = fmaxf(fmaxf(red[0], red[1]), fmaxf(red[2], red[3]));
    float s = 0.f;
    #pragma unroll
    for (int j = 0; j < 8; ++j) { v[j] = __expf(v[j] - m); s += v[j]; }
    for (int off = 32; off; off >>= 1) s += __shfl_xor(s, off);
    if (lane == 0) red[4 + wave] = s;
    __syncthreads();
    s = red[4] + red[5] + red[6] + red[7];
    float inv = 1.0f / s;
    float* bb = batt + (size_t)b * C_LEN;
    #pragma unroll
    for (int j = 0; j < 8; ++j) bb[j * 256 + tid] = v[j] * inv;
}

// ---------- q2c[b,d] = sum_c b_att[b,c] * cbf[b,c,d] (chunked + atomic) ----------
__global__ __launch_bounds__(256) void q2c_kernel(const float* __restrict__ batt,
                                                  const u16* __restrict__ cbf,
                                                  float* __restrict__ q2c) {
    int d  = blockIdx.x * 256 + threadIdx.x;
    int b  = blockIdx.y;
    int c0 = blockIdx.z * 256;
    const u16* cb = cbf + ((size_t)b * C_LEN + c0) * D_DIM + d;
    const float* bb = batt + (size_t)b * C_LEN + c0;
    float s = 0.f;
    #pragma unroll 4
    for (int i = 0; i < 256; ++i) s += bb[i] * bf2f(cb[(size_t)i * D_DIM]);
    atomicAdd(&q2c[(size_t)b * D_DIM + d], s);
}

extern "C" void kernel_launch(void* const* d_in, const int* in_sizes, int n_in,
                              void* d_out, int out_size, void* d_ws, size_t ws_size,
                              hipStream_t stream) {
    const float* c   = (const float*)d_in[0];
    const float* q   = (const float*)d_in[1];
    const float* wcq = (const float*)d_in[2];
    // b_cq (d_in[3]), b_c (d_in[5]), b_q (d_in[7]) cancel in both softmaxes — unused.
    const float* w_c = (const float*)d_in[4];
    const float* w_q = (const float*)d_in[6];
    const float* W_l = (const float*)d_in[8];
    const float* b_l = (const float*)d_in[9];
    float* out = (float*)d_out;

    char* ws = (char*)d_ws;
    // Region plan (MiB), lifetime-safe re-use:
    //   [0,32)    cbf                       (prep .. gemm2)
    //   [32,96)   CC interleaved c2q|cc2q   (written gemm<1>, read gemm2)
    //             before gemm<1>: S fp32 @32..64, qwbf @64..72
    //   [96,112)  P bf16 (softmax..gemm<1>), then Wm (wmerge_all..gemm2)
    //   [112,120) qT (prep..gemm<1>), then Wbf compact 4MiB (wmerge_all..gemm2)
    //   [120,...) smalls
    u16*   cbf     = (u16*)ws;
    float* S       = (float*)(ws + 33554432);
    u16*   CC      = (u16*)(ws + 33554432);
    u16*   qwbf    = (u16*)(ws + 67108864);
    u16*   P       = (u16*)(ws + 100663296);
    u16*   Wm      = (u16*)(ws + 100663296);
    u16*   qT      = (u16*)(ws + 117440512);
    u16*   Wbf     = (u16*)(ws + 117440512);
    float* rowterm = (float*)(ws + 125829120);
    float* colterm = (float*)(ws + 125894656);
    float* mbuf    = (float*)(ws + 125911040);
    float* batt    = (float*)(ws + 125976576);
    float* q2c     = (float*)(ws + 126042112);   // total ~120.3 MiB

    prep_kernel<<<dim3(9248), dim3(256), 0, stream>>>(c, q, wcq, w_c, w_q,
                                                      cbf, qwbf, qT, rowterm, colterm, q2c);
    gemm_async<0><<<dim3(512), dim3(256), 0, stream>>>(cbf, nullptr, nullptr, qwbf, nullptr, S, nullptr, nullptr);
    softmax_kernel<<<dim3(4096), dim3(256), 0, stream>>>(S, colterm, P, mbuf);
    batt_kernel<<<dim3(8), dim3(256), 0, stream>>>(mbuf, rowterm, batt);
    q2c_kernel<<<dim3(4, 8, 8), dim3(256), 0, stream>>>(batt, cbf, q2c);
    gemm_async<1><<<dim3(1024), dim3(256), 0, stream>>>(P, cbf, nullptr, qT, nullptr, nullptr, CC, nullptr);
    wmerge_all<<<dim3(1024), dim3(256), 0, stream>>>(W_l, q2c, Wm, Wbf);
    gemm2_8ph<<<dim3(256), dim3(512), 0, stream>>>(cbf, CC, Wm, Wbf, out, b_l);
}

// Round 4
// 346.937 us; speedup vs baseline: 1.0482x; 1.0056x over previous
//
#include <hip/hip_runtime.h>

typedef unsigned short u16;
typedef __attribute__((ext_vector_type(4))) float floatx4;
typedef __attribute__((ext_vector_type(4))) unsigned short u16x4;
typedef __attribute__((ext_vector_type(8))) short short8;
typedef __attribute__((ext_vector_type(8))) __bf16 bf16x8;

#define B_SZ 8
#define C_LEN 2048
#define Q_LEN 512
#define D_DIM 1024
#define K4 (4 * D_DIM)

static __device__ __forceinline__ u16 f2bf(float f) {
    union { float f; unsigned int u; } v; v.f = f;
    unsigned int r = v.u + 0x7FFFu + ((v.u >> 16) & 1u);  // round-to-nearest-even
    return (u16)(r >> 16);
}
static __device__ __forceinline__ float bf2f(u16 h) {
    union { unsigned int u; float f; } v; v.u = ((unsigned int)h) << 16;
    return v.f;
}

// async global->LDS, 16B per lane; LDS dest = wave-uniform base + lane*16
static __device__ __forceinline__ void async16(const void* g, void* l) {
    __builtin_amdgcn_global_load_lds(
        (const __attribute__((address_space(1))) unsigned int*)g,
        (__attribute__((address_space(3))) unsigned int*)(unsigned int)(unsigned long long)l,
        16, 0, 0);
}

// ---------- fused prep: precast_c | precast_q | transpose_q | zero q2c ----------
__global__ __launch_bounds__(256) void prep_kernel(
    const float* __restrict__ c, const float* __restrict__ q,
    const float* __restrict__ w_cq, const float* __restrict__ w_c, const float* __restrict__ w_q,
    u16* __restrict__ cbf, u16* __restrict__ qwbf, u16* __restrict__ qT,
    float* __restrict__ rowterm, float* __restrict__ colterm, float* __restrict__ q2c) {
    int blk = blockIdx.x;
    int tid = threadIdx.x;
    if (blk < 4096) {
        // precast_c: cbf = bf16(c); rowterm = c . w_c
        int row = blk * 4 + (tid >> 6);
        int lane = tid & 63;
        const float* src = c + (size_t)row * D_DIM;
        u16* dst = cbf + (size_t)row * D_DIM;
        float s = 0.f;
        #pragma unroll
        for (int j = 0; j < 4; ++j) {
            int idx = j * 256 + lane * 4;
            floatx4 a = *(const floatx4*)(src + idx);
            floatx4 w = *(const floatx4*)(w_c + idx);
            s += a[0]*w[0] + a[1]*w[1] + a[2]*w[2] + a[3]*w[3];
            u16x4 o;
            #pragma unroll
            for (int e = 0; e < 4; ++e) o[e] = f2bf(a[e]);
            *(u16x4*)(dst + idx) = o;
        }
        for (int off = 32; off; off >>= 1) s += __shfl_down(s, off);
        if (lane == 0) rowterm[row] = s;
    } else if (blk < 5120) {
        // precast_q: qwbf = bf16(q .* w_cq); colterm = q . w_q
        int row = (blk - 4096) * 4 + (tid >> 6);
        int lane = tid & 63;
        const float* src = q + (size_t)row * D_DIM;
        u16* dst = qwbf + (size_t)row * D_DIM;
        float s = 0.f;
        #pragma unroll
        for (int j = 0; j < 4; ++j) {
            int idx = j * 256 + lane * 4;
            floatx4 a  = *(const floatx4*)(src + idx);
            floatx4 wc = *(const floatx4*)(w_cq + idx);
            floatx4 wq = *(const floatx4*)(w_q + idx);
            s += a[0]*wq[0] + a[1]*wq[1] + a[2]*wq[2] + a[3]*wq[3];
            u16x4 o;
            #pragma unroll
            for (int e = 0; e < 4; ++e) o[e] = f2bf(a[e] * wc[e]);
            *(u16x4*)(dst + idx) = o;
        }
        for (int off = 32; off; off >>= 1) s += __shfl_down(s, off);
        if (lane == 0) colterm[row] = s;
    } else if (blk < 9216) {
        // transpose_q: qT[b,d,q] = bf16(q[b,q,d])
        __shared__ float tile[32][33];
        int t = blk - 5120;
        int q0 = (t & 15) * 32;
        int d0 = ((t >> 4) & 31) * 32;
        int b = t >> 9;
        int tx = tid & 31, ty = tid >> 5;  // 32 x 8
        const float* qb = q + (size_t)b * Q_LEN * D_DIM;
        #pragma unroll
        for (int j = 0; j < 4; ++j) {
            int row = ty + j * 8;
            tile[row][tx] = qb[(size_t)(q0 + row) * D_DIM + d0 + tx];
        }
        __syncthreads();
        u16* qTb = qT + (size_t)b * D_DIM * Q_LEN;
        #pragma unroll
        for (int j = 0; j < 4; ++j) {
            int row = ty + j * 8;
            qTb[(size_t)(d0 + row) * Q_LEN + q0 + tx] = f2bf(tile[tx][row]);
        }
    } else {
        // zero q2c (8192 floats)
        int i = (blk - 9216) * 256 + tid;
        q2c[i] = 0.0f;
    }
}

// ---------- fused W prep: Wm[b,n,k] = bf16(W1 + W4*q2c); Wbf[n,kk] = bf16(W[n,1024+kk]) ----------
__global__ __launch_bounds__(256) void wmerge_all(const float* __restrict__ W, const float* __restrict__ q2c,
                                                  u16* __restrict__ Wm, u16* __restrict__ Wbf) {
    int n = blockIdx.x;             // 1024 rows
    int k = threadIdx.x * 4;        // 0..1023
    const float* wr = W + (size_t)n * K4;
    floatx4 w1 = *(const floatx4*)(wr + k);
    floatx4 w4 = *(const floatx4*)(wr + 3072 + k);
    #pragma unroll
    for (int p = 0; p < 2; ++p) {
        int kk = p * 1024 + k;
        floatx4 v = *(const floatx4*)(wr + 1024 + kk);
        u16x4 o;
        #pragma unroll
        for (int e = 0; e < 4; ++e) o[e] = f2bf(v[e]);
        *(u16x4*)(Wbf + (size_t)n * 2048 + kk) = o;
    }
    #pragma unroll
    for (int b = 0; b < 8; ++b) {
        floatx4 g = *(const floatx4*)(q2c + (size_t)b * D_DIM + k);
        u16x4 o;
        #pragma unroll
        for (int e = 0; e < 4; ++e) o[e] = f2bf(w1[e] + w4[e] * g[e]);
        *(u16x4*)(Wm + (size_t)b * 1048576 + (size_t)n * 1024 + k) = o;
    }
}

// ---------- unified async bf16 GEMM, C = A @ B^T, 128x128 tile, BK=64, swizzled LDS ----------
// (kept for MODE 0 and MODE 1; MODE 2 uses gemm2_8ph below)
template<int MODE>
__global__ __launch_bounds__(256) void gemm_async(
    const u16* __restrict__ A0, const u16* __restrict__ A1, const u16* __restrict__ A2,
    const u16* __restrict__ B0, const u16* __restrict__ B1,
    float* __restrict__ of, u16* __restrict__ ob, const float* __restrict__ bias) {
    constexpr int NSEC = (MODE == 2) ? 3 : 1;
    constexpr int KSEC = (MODE == 1) ? 512 : 1024;
    constexpr int LDO  = (MODE == 0) ? 512 : 1024;
    constexpr int NTILES = (MODE == 0) ? 4 : 8;
    __shared__ u16 As[128 * 64];
    __shared__ u16 Bs[128 * 64];
    const int tid  = threadIdx.x;
    const int lane = tid & 63;
    const int wave = tid >> 6;
    const int lin  = blockIdx.x;
    const int b    = lin & 7;            // XCD pin
    const int rem  = lin >> 3;
    const int n0   = (rem % NTILES) * 128;
    const int m0   = (rem / NTILES) * 128;

    const u16* Aarr[NSEC];
    const u16* Barr[NSEC];
    int lda_[NSEC], ldb_[NSEC];
    if constexpr (MODE == 0) {
        Aarr[0] = A0 + (size_t)b * C_LEN * D_DIM; lda_[0] = 1024;
        Barr[0] = B0 + (size_t)b * Q_LEN * D_DIM; ldb_[0] = 1024;
    } else if constexpr (MODE == 1) {
        Aarr[0] = A0 + (size_t)b * C_LEN * Q_LEN; lda_[0] = 512;
        Barr[0] = B0 + (size_t)b * D_DIM * Q_LEN; ldb_[0] = 512;
    } else {
        Aarr[0] = A0 + (size_t)b * C_LEN * D_DIM;  lda_[0] = 1024;
        Barr[0] = B0 + (size_t)b * D_DIM * D_DIM;  ldb_[0] = 1024;   // Wm (per-batch)
        Aarr[1] = A1 + (size_t)b * C_LEN * 2048;        lda_[1] = 2048;  // CC + 0
        Barr[1] = B1;                                   ldb_[1] = 2048;  // Wbf + 0
        Aarr[2] = A1 + (size_t)b * C_LEN * 2048 + 1024; lda_[2] = 2048;  // CC + 1024
        Barr[2] = B1 + 1024;                            ldb_[2] = 2048;  // Wbf + 1024
    }

    // staging geometry: 16 chunks of 8 rows; wave w stages chunks 4w..4w+3
    const int srow = lane >> 3;                    // 0..7 row-within-chunk
    const int ssc  = ((lane & 7) ^ srow) * 8;      // swizzled source column (u16)

    floatx4 acc[4][4];
    #pragma unroll
    for (int i = 0; i < 4; ++i)
        #pragma unroll
        for (int j = 0; j < 4; ++j)
            acc[i][j] = (floatx4)(0.0f);

    const int wrow = (wave >> 1) * 64;
    const int wcol = (wave & 1) * 64;
    const int quad = lane >> 4;
    const int lrow = lane & 15;
    const int sw7  = lane & 7;                     // row&7 for all reader rows

    #pragma unroll
    for (int sec = 0; sec < NSEC; ++sec) {
        const u16* __restrict__ Ab = Aarr[sec];
        const u16* __restrict__ Bb = Barr[sec];
        const int LA = lda_[sec];
        const int LB = ldb_[sec];
        for (int k0 = 0; k0 < KSEC; k0 += 64) {
            #pragma unroll
            for (int cc = 0; cc < 4; ++cc) {
                int ch = wave * 4 + cc;
                int rr = ch * 8 + srow;
                async16(Ab + (size_t)(m0 + rr) * LA + k0 + ssc, &As[ch * 512]);
            }
            #pragma unroll
            for (int cc = 0; cc < 4; ++cc) {
                int ch = wave * 4 + cc;
                int rr = ch * 8 + srow;
                async16(Bb + (size_t)(n0 + rr) * LB + k0 + ssc, &Bs[ch * 512]);
            }
            __syncthreads();
            #pragma unroll
            for (int h = 0; h < 2; ++h) {
                const int pc = ((h * 4 + quad) ^ sw7) * 8;   // physical column (u16)
                bf16x8 af[4], bfr[4];
                #pragma unroll
                for (int i = 0; i < 4; ++i)
                    af[i] = __builtin_bit_cast(bf16x8, *(const short8*)&As[(wrow + i*16 + lrow) * 64 + pc]);
                #pragma unroll
                for (int j = 0; j < 4; ++j)
                    bfr[j] = __builtin_bit_cast(bf16x8, *(const short8*)&Bs[(wcol + j*16 + lrow) * 64 + pc]);
                #pragma unroll
                for (int i = 0; i < 4; ++i)
                    #pragma unroll
                    for (int j = 0; j < 4; ++j)
                        acc[i][j] = __builtin_amdgcn_mfma_f32_16x16x32_bf16(af[i], bfr[j], acc[i][j], 0, 0, 0);
            }
            __syncthreads();
        }
    }

    // ---- epilogue; C/D layout: col = lane&15, row = quad*4 + reg ----
    float* ofb = nullptr; u16* ccb = nullptr; const u16* cbr = nullptr;
    if (MODE == 0)      ofb = of + (size_t)b * C_LEN * Q_LEN;
    else if (MODE == 1) { ccb = ob + (size_t)b * C_LEN * 2048; cbr = A1 + (size_t)b * C_LEN * D_DIM; }
    else                ofb = of + (size_t)b * C_LEN * D_DIM;
    #pragma unroll
    for (int i = 0; i < 4; ++i) {
        #pragma unroll
        for (int j = 0; j < 4; ++j) {
            #pragma unroll
            for (int e = 0; e < 4; ++e) {
                int gm = m0 + wrow + i * 16 + quad * 4 + e;
                int gn = n0 + wcol + j * 16 + lrow;
                float v = acc[i][j][e];
                if (MODE == 0)      ofb[(size_t)gm * LDO + gn] = v;
                else if (MODE == 1) {
                    u16 p = f2bf(v);
                    float cv = bf2f(cbr[(size_t)gm * 1024 + gn]);
                    ccb[(size_t)gm * 2048 + gn]        = p;
                    ccb[(size_t)gm * 2048 + 1024 + gn] = f2bf(cv * bf2f(p));
                }
                else                ofb[(size_t)gm * LDO + gn] = v + bias[gn];
            }
        }
    }
}

// ---------- 256x256-tile, 4-phase, counted-vmcnt bf16 GEMM for the output projection ----------
// z[b] = cbf[b] @ Wm[b]^T + CC0[b] @ Wbf0^T + CC1[b] @ Wbf1^T + b_l   (K = 3*1024 = 48 tiles of 64)
//
// Round-3 postmortem: bank conflicts are now 0 (swizzle verified) but MfmaUtil
// stalled at 40% — the sched_barrier(0) pins around every barrier were defeating
// the compiler's scheduling (m141: order-pinning = 874->510 TF). Round 4 removes
// ALL sched_barrier(0): ordering is carried by SSA deps (visible ds_reads -> MFMA),
// the "memory" clobber on VMW (loads can't cross), and side-effect ordering of
// global_load_lds / s_barrier intrinsics. No inline-asm ds_read => rule-18 N/A.
//
// Liveness (full-K units [256][64], 2 buffers, PROVEN swizzle chunk^=(row&7)):
//   * A(t) last read @p3, B(t) last read @p2 (p3 reuses B frags from registers).
//   * Stage slots: A(t+1) @p0(t) (opposite buffer); B(t+2) @p3(t) (same buffer,
//     B(t) drained at p2(t) end barrier).
//   * vmcnt(4) at p3(t) end leaves only B(t+2) in flight => A(t+1), B(t+1) landed
//     before tile t+1. Never drains to 0 in steady state; tail (tt>=46) drains.
#define BAR8() __builtin_amdgcn_s_barrier()
#define VMW(N) do { asm volatile("s_waitcnt vmcnt(" #N ")" ::: "memory"); } while (0)

#define LDA4(DST, MQ, KH, CUR) do { \
    const u16* un_ = lds_ + (CUR) * 32768; \
    _Pragma("unroll") \
    for (int i_ = 0; i_ < 4; ++i_) \
      (DST)[i_] = __builtin_bit_cast(bf16x8, \
          *(const short8*)(un_ + (wm * 128 + (MQ) * 64 + i_ * 16 + lrow) * 64 + pca[KH])); \
  } while (0)

#define LDB4(DST, KH, CUR) do { \
    const u16* un_ = lds_ + (CUR) * 32768 + 16384; \
    _Pragma("unroll") \
    for (int i_ = 0; i_ < 4; ++i_) \
      (DST)[i_] = __builtin_bit_cast(bf16x8, \
          *(const short8*)(un_ + (wn * 64 + i_ * 16 + lrow) * 64 + pca[KH])); \
  } while (0)

#define MFMA16(MQ4, A_, B_) do { \
    __builtin_amdgcn_s_setprio(1); \
    _Pragma("unroll") \
    for (int i_ = 0; i_ < 4; ++i_) { \
      _Pragma("unroll") \
      for (int j_ = 0; j_ < 4; ++j_) \
        acc[(MQ4) + i_][j_] = __builtin_amdgcn_mfma_f32_16x16x32_bf16( \
            (A_)[i_], (B_)[j_], acc[(MQ4) + i_][j_], 0, 0, 0); \
    } \
    __builtin_amdgcn_s_setprio(0); \
  } while (0)

__global__ __launch_bounds__(512, 2) void gemm2_8ph(
    const u16* __restrict__ cbf, const u16* __restrict__ CC,
    const u16* __restrict__ Wm, const u16* __restrict__ Wbf,
    float* __restrict__ of, const float* __restrict__ bias) {
    __shared__ __align__(16) u16 lds_[65536];  // [buf2][A|B][row256][col64] = 128 KiB
    const int tid  = threadIdx.x;
    const int lane = tid & 63;
    const int wave = tid >> 6;          // 8 waves: 2 (M) x 4 (N)
    const int lin  = blockIdx.x;
    const int b    = lin & 7;           // XCD pin: one batch per XCD
    const int rem  = lin >> 3;          // 0..31 -> 8 m-tiles x 4 n-tiles
    const int n0   = (rem & 3) * 256;
    const int m0   = (rem >> 2) * 256;
    const int wm   = wave >> 2;         // 0..1  -> rows m0+wm*128 .. +127
    const int wn   = wave & 3;          // 0..3  -> cols n0+wn*64 .. +63
    const int quad = lane >> 4;
    const int lrow = lane & 15;
    const int lr7  = lane & 7;          // == row&7 for every fragment-read row
    // physical 16B chunk (u16 offset) for logical k-chunk (KH*4 + quad):
    const int pca[2] = { ((0 + quad) ^ lr7) * 8, ((4 + quad) ^ lr7) * 8 };

    const u16* Acb  = cbf + (size_t)b * (C_LEN * D_DIM);
    const u16* Acc0 = CC  + (size_t)b * (C_LEN * 2048);
    const u16* Acc1 = Acc0 + 1024;
    const u16* Bwm  = Wm  + (size_t)b * (D_DIM * D_DIM);

    // stage a full [256][64] unit (ab: 0=A,1=B) of tile tt into LDS buffer tt&1.
    // linear LDS dest (wave-uniform base; HW adds lane*16), inverse-swizzled source:
    // LDS[row][pchunk] = global[row][pchunk ^ (row&7)]  (8 chunks of 16B per row).
    auto STAGE = [&](int tt, int ab) {
        const int sec = tt >> 4;                    // 3 K-sections of 16 tiles
        const int kl  = (tt & 15) * 64;             // local k within section
        const u16* base;
        int r0;
        if (ab == 0) { base = (sec == 0) ? Acb : (sec == 1) ? Acc0 : Acc1; r0 = m0; }
        else         { base = (sec == 0) ? Bwm : (sec == 1) ? Wbf  : Wbf + 1024; r0 = n0; }
        const int ld = (sec == 0) ? 1024 : 2048;
        u16* unit = lds_ + (tt & 1) * 32768 + ab * 16384;
        #pragma unroll
        for (int l = 0; l < 4; ++l) {
            const int li  = l * 512 + tid;          // 0..2047 -> (row, chunk)
            const int row = li >> 3;
            const int sc  = (li & 7) ^ (row & 7);   // inverse swizzle on global col
            async16(base + (size_t)(r0 + row) * ld + kl + sc * 8,
                    unit + (size_t)(l * 512 + (tid & ~63)) * 8);
        }
    };

    floatx4 acc[8][4];
    #pragma unroll
    for (int i = 0; i < 8; ++i)
        #pragma unroll
        for (int j = 0; j < 4; ++j) acc[i][j] = (floatx4)(0.0f);

    // prologue: A(0), B(0), B(1); A(1) is staged at p0(0).
    STAGE(0, 0); STAGE(0, 1); STAGE(1, 1);
    VMW(4);                        // A(0), B(0) landed; B(1) in flight
    BAR8();

    bf16x8 af[4], bf[4];
    for (int tt = 0; tt < 48; ++tt) {
        const int cur = tt & 1;
        // ---- p0: acc rows 0-3, kh0 ----
        if (tt + 1 < 48) STAGE(tt + 1, 0);        // A(t+1) -> opposite buffer
        LDA4(af, 0, 0, cur);
        LDB4(bf, 0, cur);
        BAR8();
        MFMA16(0, af, bf);
        BAR8();
        // ---- p1: acc rows 4-7, kh0 (B frags reused from regs) ----
        LDA4(af, 1, 0, cur);
        BAR8();
        MFMA16(4, af, bf);
        BAR8();
        // ---- p2: acc rows 0-3, kh1 (last read of B(t)) ----
        LDA4(af, 0, 1, cur);
        LDB4(bf, 1, cur);
        BAR8();
        MFMA16(0, af, bf);
        BAR8();
        // ---- p3: acc rows 4-7, kh1 (last read of A(t)) ----
        if (tt + 2 < 48) STAGE(tt + 2, 1);        // B(t+2) -> same buffer (B(t) drained)
        LDA4(af, 1, 1, cur);
        BAR8();
        MFMA16(4, af, bf);
        if (tt < 46) { VMW(4); } else { VMW(0); } // leave only B(t+2) in flight
        BAR8();
    }

    // ---- epilogue; C/D layout: col = lane&15, row = quad*4 + reg ----
    float bs[4];
    #pragma unroll
    for (int j = 0; j < 4; ++j) bs[j] = bias[n0 + wn * 64 + j * 16 + lrow];
    float* ofb = of + (size_t)b * (C_LEN * D_DIM);
    #pragma unroll
    for (int i = 0; i < 8; ++i) {
        #pragma unroll
        for (int j = 0; j < 4; ++j) {
            #pragma unroll
            for (int e = 0; e < 4; ++e) {
                const int gm = m0 + wm * 128 + i * 16 + quad * 4 + e;
                const int gn = n0 + wn * 64 + j * 16 + lrow;
                ofb[(size_t)gm * D_DIM + gn] = acc[i][j][e] + bs[j];
            }
        }
    }
}

// ---------- softmax over Q per (b,c) row; also record rowmax ----------
__global__ void softmax_kernel(const float* __restrict__ S, const float* __restrict__ colterm,
                               u16* __restrict__ P, float* __restrict__ mbuf) {
    int row = blockIdx.x * 4 + (threadIdx.x >> 6);
    int lane = threadIdx.x & 63;
    int b = row >> 11;  // C_LEN = 2048
    const float* sp = S + (size_t)row * Q_LEN;
    const float* cp = colterm + (size_t)b * Q_LEN;
    float v[8];
    float m = -1e30f;
    #pragma unroll
    for (int j = 0; j < 8; ++j) {
        int idx = j * 64 + lane;
        v[j] = sp[idx] + cp[idx];
        m = fmaxf(m, v[j]);
    }
    for (int off = 32; off; off >>= 1) m = fmaxf(m, __shfl_xor(m, off));
    float s = 0.f;
    #pragma unroll
    for (int j = 0; j < 8; ++j) { v[j] = __expf(v[j] - m); s += v[j]; }
    for (int off = 32; off; off >>= 1) s += __shfl_xor(s, off);
    float inv = 1.0f / s;
    u16* pp = P + (size_t)row * Q_LEN;
    #pragma unroll
    for (int j = 0; j < 8; ++j) pp[j * 64 + lane] = f2bf(v[j] * inv);
    if (lane == 0) mbuf[row] = m;
}

// ---------- b_att[b,c] = softmax_c(rowmax + rowterm) ----------
__global__ __launch_bounds__(256) void batt_kernel(const float* __restrict__ mbuf,
                                                   const float* __restrict__ rowterm,
                                                   float* __restrict__ batt) {
    __shared__ float red[8];
    int b = blockIdx.x;
    int tid = threadIdx.x;
    const float* mb = mbuf + (size_t)b * C_LEN;
    const float* rt = rowterm + (size_t)b * C_LEN;
    float v[8];
    float m = -1e30f;
    #pragma unroll
    for (int j = 0; j < 8; ++j) { int idx = j * 256 + tid; v[j] = mb[idx] + rt[idx]; m = fmaxf(m, v[j]); }
    for (int off = 32; off; off >>= 1) m = fmaxf(m, __shfl_xor(m, off));
    int wave = tid >> 6, lane = tid & 63;
    if (lane == 0) red[wave] = m;
    __syncthreads();
    m = fmaxf(fmaxf(red[0], red[1]), fmaxf(red[2], red[3]));
    float s = 0.f;
    #pragma unroll
    for (int j = 0; j < 8; ++j) { v[j] = __expf(v[j] - m); s += v[j]; }
    for (int off = 32; off; off >>= 1) s += __shfl_xor(s, off);
    if (lane == 0) red[4 + wave] = s;
    __syncthreads();
    s = red[4] + red[5] + red[6] + red[7];
    float inv = 1.0f / s;
    float* bb = batt + (size_t)b * C_LEN;
    #pragma unroll
    for (int j = 0; j < 8; ++j) bb[j * 256 + tid] = v[j] * inv;
}

// ---------- q2c[b,d] = sum_c b_att[b,c] * cbf[b,c,d] (chunked + atomic) ----------
__global__ __launch_bounds__(256) void q2c_kernel(const float* __restrict__ batt,
                                                  const u16* __restrict__ cbf,
                                                  float* __restrict__ q2c) {
    int d  = blockIdx.x * 256 + threadIdx.x;
    int b  = blockIdx.y;
    int c0 = blockIdx.z * 256;
    const u16* cb = cbf + ((size_t)b * C_LEN + c0) * D_DIM + d;
    const float* bb = batt + (size_t)b * C_LEN + c0;
    float s = 0.f;
    #pragma unroll 4
    for (int i = 0; i < 256; ++i) s += bb[i] * bf2f(cb[(size_t)i * D_DIM]);
    atomicAdd(&q2c[(size_t)b * D_DIM + d], s);
}

extern "C" void kernel_launch(void* const* d_in, const int* in_sizes, int n_in,
                              void* d_out, int out_size, void* d_ws, size_t ws_size,
                              hipStream_t stream) {
    const float* c   = (const float*)d_in[0];
    const float* q   = (const float*)d_in[1];
    const float* wcq = (const float*)d_in[2];
    // b_cq (d_in[3]), b_c (d_in[5]), b_q (d_in[7]) cancel in both softmaxes — unused.
    const float* w_c = (const float*)d_in[4];
    const float* w_q = (const float*)d_in[6];
    const float* W_l = (const float*)d_in[8];
    const float* b_l = (const float*)d_in[9];
    float* out = (float*)d_out;

    char* ws = (char*)d_ws;
    // Region plan (MiB), lifetime-safe re-use:
    //   [0,32)    cbf                       (prep .. gemm2)
    //   [32,96)   CC interleaved c2q|cc2q   (written gemm<1>, read gemm2)
    //             before gemm<1>: S fp32 @32..64, qwbf @64..72
    //   [96,112)  P bf16 (softmax..gemm<1>), then Wm (wmerge_all..gemm2)
    //   [112,120) qT (prep..gemm<1>), then Wbf compact 4MiB (wmerge_all..gemm2)
    //   [120,...) smalls
    u16*   cbf     = (u16*)ws;
    float* S       = (float*)(ws + 33554432);
    u16*   CC      = (u16*)(ws + 33554432);
    u16*   qwbf    = (u16*)(ws + 67108864);
    u16*   P       = (u16*)(ws + 100663296);
    u16*   Wm      = (u16*)(ws + 100663296);
    u16*   qT      = (u16*)(ws + 117440512);
    u16*   Wbf     = (u16*)(ws + 117440512);
    float* rowterm = (float*)(ws + 125829120);
    float* colterm = (float*)(ws + 125894656);
    float* mbuf    = (float*)(ws + 125911040);
    float* batt    = (float*)(ws + 125976576);
    float* q2c     = (float*)(ws + 126042112);   // total ~120.3 MiB

    prep_kernel<<<dim3(9248), dim3(256), 0, stream>>>(c, q, wcq, w_c, w_q,
                                                      cbf, qwbf, qT, rowterm, colterm, q2c);
    gemm_async<0><<<dim3(512), dim3(256), 0, stream>>>(cbf, nullptr, nullptr, qwbf, nullptr, S, nullptr, nullptr);
    softmax_kernel<<<dim3(4096), dim3(256), 0, stream>>>(S, colterm, P, mbuf);
    batt_kernel<<<dim3(8), dim3(256), 0, stream>>>(mbuf, rowterm, batt);
    q2c_kernel<<<dim3(4, 8, 8), dim3(256), 0, stream>>>(batt, cbf, q2c);
    gemm_async<1><<<dim3(1024), dim3(256), 0, stream>>>(P, cbf, nullptr, qT, nullptr, nullptr, CC, nullptr);
    wmerge_all<<<dim3(1024), dim3(256), 0, stream>>>(W_l, q2c, Wm, Wbf);
    gemm2_8ph<<<dim3(256), dim3(512), 0, stream>>>(cbf, CC, Wm, Wbf, out, b_l);
}

// Round 6
// 346.576 us; speedup vs baseline: 1.0493x; 1.0010x over previous
//
#include <hip/hip_runtime.h>

typedef unsigned short u16;
typedef __attribute__((ext_vector_type(4))) float floatx4;
typedef __attribute__((ext_vector_type(4))) unsigned short u16x4;
typedef __attribute__((ext_vector_type(8))) short short8;
typedef __attribute__((ext_vector_type(8))) __bf16 bf16x8;

#define B_SZ 8
#define C_LEN 2048
#define Q_LEN 512
#define D_DIM 1024
#define K4 (4 * D_DIM)

static __device__ __forceinline__ u16 f2bf(float f) {
    union { float f; unsigned int u; } v; v.f = f;
    unsigned int r = v.u + 0x7FFFu + ((v.u >> 16) & 1u);  // round-to-nearest-even
    return (u16)(r >> 16);
}
static __device__ __forceinline__ float bf2f(u16 h) {
    union { unsigned int u; float f; } v; v.u = ((unsigned int)h) << 16;
    return v.f;
}

// async global->LDS, 16B per lane; LDS dest = wave-uniform base + lane*16
static __device__ __forceinline__ void async16(const void* g, void* l) {
    __builtin_amdgcn_global_load_lds(
        (const __attribute__((address_space(1))) unsigned int*)g,
        (__attribute__((address_space(3))) unsigned int*)(unsigned int)(unsigned long long)l,
        16, 0, 0);
}

// ---------- fused prep: precast_c | precast_q | transpose_q | zero q2c ----------
__global__ __launch_bounds__(256) void prep_kernel(
    const float* __restrict__ c, const float* __restrict__ q,
    const float* __restrict__ w_cq, const float* __restrict__ w_c, const float* __restrict__ w_q,
    u16* __restrict__ cbf, u16* __restrict__ qwbf, u16* __restrict__ qT,
    float* __restrict__ rowterm, float* __restrict__ colterm, float* __restrict__ q2c) {
    int blk = blockIdx.x;
    int tid = threadIdx.x;
    if (blk < 4096) {
        // precast_c: cbf = bf16(c); rowterm = c . w_c
        int row = blk * 4 + (tid >> 6);
        int lane = tid & 63;
        const float* src = c + (size_t)row * D_DIM;
        u16* dst = cbf + (size_t)row * D_DIM;
        float s = 0.f;
        #pragma unroll
        for (int j = 0; j < 4; ++j) {
            int idx = j * 256 + lane * 4;
            floatx4 a = *(const floatx4*)(src + idx);
            floatx4 w = *(const floatx4*)(w_c + idx);
            s += a[0]*w[0] + a[1]*w[1] + a[2]*w[2] + a[3]*w[3];
            u16x4 o;
            #pragma unroll
            for (int e = 0; e < 4; ++e) o[e] = f2bf(a[e]);
            *(u16x4*)(dst + idx) = o;
        }
        for (int off = 32; off; off >>= 1) s += __shfl_down(s, off);
        if (lane == 0) rowterm[row] = s;
    } else if (blk < 5120) {
        // precast_q: qwbf = bf16(q .* w_cq); colterm = q . w_q
        int row = (blk - 4096) * 4 + (tid >> 6);
        int lane = tid & 63;
        const float* src = q + (size_t)row * D_DIM;
        u16* dst = qwbf + (size_t)row * D_DIM;
        float s = 0.f;
        #pragma unroll
        for (int j = 0; j < 4; ++j) {
            int idx = j * 256 + lane * 4;
            floatx4 a  = *(const floatx4*)(src + idx);
            floatx4 wc = *(const floatx4*)(w_cq + idx);
            floatx4 wq = *(const floatx4*)(w_q + idx);
            s += a[0]*wq[0] + a[1]*wq[1] + a[2]*wq[2] + a[3]*wq[3];
            u16x4 o;
            #pragma unroll
            for (int e = 0; e < 4; ++e) o[e] = f2bf(a[e] * wc[e]);
            *(u16x4*)(dst + idx) = o;
        }
        for (int off = 32; off; off >>= 1) s += __shfl_down(s, off);
        if (lane == 0) colterm[row] = s;
    } else if (blk < 9216) {
        // transpose_q: qT[b,d,q] = bf16(q[b,q,d])
        __shared__ float tile[32][33];
        int t = blk - 5120;
        int q0 = (t & 15) * 32;
        int d0 = ((t >> 4) & 31) * 32;
        int b = t >> 9;
        int tx = tid & 31, ty = tid >> 5;  // 32 x 8
        const float* qb = q + (size_t)b * Q_LEN * D_DIM;
        #pragma unroll
        for (int j = 0; j < 4; ++j) {
            int row = ty + j * 8;
            tile[row][tx] = qb[(size_t)(q0 + row) * D_DIM + d0 + tx];
        }
        __syncthreads();
        u16* qTb = qT + (size_t)b * D_DIM * Q_LEN;
        #pragma unroll
        for (int j = 0; j < 4; ++j) {
            int row = ty + j * 8;
            qTb[(size_t)(d0 + row) * Q_LEN + q0 + tx] = f2bf(tile[tx][row]);
        }
    } else {
        // zero q2c (8192 floats)
        int i = (blk - 9216) * 256 + tid;
        q2c[i] = 0.0f;
    }
}

// ---------- fused W prep: Wm[b,n,k] = bf16(W1 + W4*q2c); Wbf[n,kk] = bf16(W[n,1024+kk]) ----------
__global__ __launch_bounds__(256) void wmerge_all(const float* __restrict__ W, const float* __restrict__ q2c,
                                                  u16* __restrict__ Wm, u16* __restrict__ Wbf) {
    int n = blockIdx.x;             // 1024 rows
    int k = threadIdx.x * 4;        // 0..1023
    const float* wr = W + (size_t)n * K4;
    floatx4 w1 = *(const floatx4*)(wr + k);
    floatx4 w4 = *(const floatx4*)(wr + 3072 + k);
    #pragma unroll
    for (int p = 0; p < 2; ++p) {
        int kk = p * 1024 + k;
        floatx4 v = *(const floatx4*)(wr + 1024 + kk);
        u16x4 o;
        #pragma unroll
        for (int e = 0; e < 4; ++e) o[e] = f2bf(v[e]);
        *(u16x4*)(Wbf + (size_t)n * 2048 + kk) = o;
    }
    #pragma unroll
    for (int b = 0; b < 8; ++b) {
        floatx4 g = *(const floatx4*)(q2c + (size_t)b * D_DIM + k);
        u16x4 o;
        #pragma unroll
        for (int e = 0; e < 4; ++e) o[e] = f2bf(w1[e] + w4[e] * g[e]);
        *(u16x4*)(Wm + (size_t)b * 1048576 + (size_t)n * 1024 + k) = o;
    }
}

// ---------- unified async bf16 GEMM, C = A @ B^T, 128x128 tile, BK=64, swizzled LDS ----------
// (kept for MODE 0 and MODE 1; MODE 2 uses gemm2_pipe below)
template<int MODE>
__global__ __launch_bounds__(256) void gemm_async(
    const u16* __restrict__ A0, const u16* __restrict__ A1, const u16* __restrict__ A2,
    const u16* __restrict__ B0, const u16* __restrict__ B1,
    float* __restrict__ of, u16* __restrict__ ob, const float* __restrict__ bias) {
    constexpr int NSEC = (MODE == 2) ? 3 : 1;
    constexpr int KSEC = (MODE == 1) ? 512 : 1024;
    constexpr int LDO  = (MODE == 0) ? 512 : 1024;
    constexpr int NTILES = (MODE == 0) ? 4 : 8;
    __shared__ u16 As[128 * 64];
    __shared__ u16 Bs[128 * 64];
    const int tid  = threadIdx.x;
    const int lane = tid & 63;
    const int wave = tid >> 6;
    const int lin  = blockIdx.x;
    const int b    = lin & 7;            // XCD pin
    const int rem  = lin >> 3;
    const int n0   = (rem % NTILES) * 128;
    const int m0   = (rem / NTILES) * 128;

    const u16* Aarr[NSEC];
    const u16* Barr[NSEC];
    int lda_[NSEC], ldb_[NSEC];
    if constexpr (MODE == 0) {
        Aarr[0] = A0 + (size_t)b * C_LEN * D_DIM; lda_[0] = 1024;
        Barr[0] = B0 + (size_t)b * Q_LEN * D_DIM; ldb_[0] = 1024;
    } else if constexpr (MODE == 1) {
        Aarr[0] = A0 + (size_t)b * C_LEN * Q_LEN; lda_[0] = 512;
        Barr[0] = B0 + (size_t)b * D_DIM * Q_LEN; ldb_[0] = 512;
    } else {
        Aarr[0] = A0 + (size_t)b * C_LEN * D_DIM;  lda_[0] = 1024;
        Barr[0] = B0 + (size_t)b * D_DIM * D_DIM;  ldb_[0] = 1024;   // Wm (per-batch)
        Aarr[1] = A1 + (size_t)b * C_LEN * 2048;        lda_[1] = 2048;  // CC + 0
        Barr[1] = B1;                                   ldb_[1] = 2048;  // Wbf + 0
        Aarr[2] = A1 + (size_t)b * C_LEN * 2048 + 1024; lda_[2] = 2048;  // CC + 1024
        Barr[2] = B1 + 1024;                            ldb_[2] = 2048;  // Wbf + 1024
    }

    // staging geometry: 16 chunks of 8 rows; wave w stages chunks 4w..4w+3
    const int srow = lane >> 3;                    // 0..7 row-within-chunk
    const int ssc  = ((lane & 7) ^ srow) * 8;      // swizzled source column (u16)

    floatx4 acc[4][4];
    #pragma unroll
    for (int i = 0; i < 4; ++i)
        #pragma unroll
        for (int j = 0; j < 4; ++j)
            acc[i][j] = (floatx4)(0.0f);

    const int wrow = (wave >> 1) * 64;
    const int wcol = (wave & 1) * 64;
    const int quad = lane >> 4;
    const int lrow = lane & 15;
    const int sw7  = lane & 7;                     // row&7 for all reader rows

    #pragma unroll
    for (int sec = 0; sec < NSEC; ++sec) {
        const u16* __restrict__ Ab = Aarr[sec];
        const u16* __restrict__ Bb = Barr[sec];
        const int LA = lda_[sec];
        const int LB = ldb_[sec];
        for (int k0 = 0; k0 < KSEC; k0 += 64) {
            #pragma unroll
            for (int cc = 0; cc < 4; ++cc) {
                int ch = wave * 4 + cc;
                int rr = ch * 8 + srow;
                async16(Ab + (size_t)(m0 + rr) * LA + k0 + ssc, &As[ch * 512]);
            }
            #pragma unroll
            for (int cc = 0; cc < 4; ++cc) {
                int ch = wave * 4 + cc;
                int rr = ch * 8 + srow;
                async16(Bb + (size_t)(n0 + rr) * LB + k0 + ssc, &Bs[ch * 512]);
            }
            __syncthreads();
            #pragma unroll
            for (int h = 0; h < 2; ++h) {
                const int pc = ((h * 4 + quad) ^ sw7) * 8;   // physical column (u16)
                bf16x8 af[4], bfr[4];
                #pragma unroll
                for (int i = 0; i < 4; ++i)
                    af[i] = __builtin_bit_cast(bf16x8, *(const short8*)&As[(wrow + i*16 + lrow) * 64 + pc]);
                #pragma unroll
                for (int j = 0; j < 4; ++j)
                    bfr[j] = __builtin_bit_cast(bf16x8, *(const short8*)&Bs[(wcol + j*16 + lrow) * 64 + pc]);
                #pragma unroll
                for (int i = 0; i < 4; ++i)
                    #pragma unroll
                    for (int j = 0; j < 4; ++j)
                        acc[i][j] = __builtin_amdgcn_mfma_f32_16x16x32_bf16(af[i], bfr[j], acc[i][j], 0, 0, 0);
            }
            __syncthreads();
        }
    }

    // ---- epilogue; C/D layout: col = lane&15, row = quad*4 + reg ----
    float* ofb = nullptr; u16* ccb = nullptr; const u16* cbr = nullptr;
    if (MODE == 0)      ofb = of + (size_t)b * C_LEN * Q_LEN;
    else if (MODE == 1) { ccb = ob + (size_t)b * C_LEN * 2048; cbr = A1 + (size_t)b * C_LEN * D_DIM; }
    else                ofb = of + (size_t)b * C_LEN * D_DIM;
    #pragma unroll
    for (int i = 0; i < 4; ++i) {
        #pragma unroll
        for (int j = 0; j < 4; ++j) {
            #pragma unroll
            for (int e = 0; e < 4; ++e) {
                int gm = m0 + wrow + i * 16 + quad * 4 + e;
                int gn = n0 + wcol + j * 16 + lrow;
                float v = acc[i][j][e];
                if (MODE == 0)      ofb[(size_t)gm * LDO + gn] = v;
                else if (MODE == 1) {
                    u16 p = f2bf(v);
                    float cv = bf2f(cbr[(size_t)gm * 1024 + gn]);
                    ccb[(size_t)gm * 2048 + gn]        = p;
                    ccb[(size_t)gm * 2048 + 1024 + gn] = f2bf(cv * bf2f(p));
                }
                else                ofb[(size_t)gm * LDO + gn] = v + bias[gn];
            }
        }
    }
}

// ---------- 256x256-tile, 2-barrier/tile pipelined bf16 GEMM for the output projection ----------
// z[b] = cbf[b] @ Wm[b]^T + CC0[b] @ Wbf0^T + CC1[b] @ Wbf1^T + b_l   (K = 3*1024 = 48 tiles of 64)
//
// Round-4 postmortem: the 4-phase x 2-barrier schedule serialized ds_read windows
// against MFMA windows (no other block on the CU to fill the gap) -> ~725 cyc
// overhead per phase, MfmaUtil stuck at 40%. This version interleaves fragment
// reads INSIDE the MFMA stream (compiler's fine-grained lgkmcnt hides their
// latency under MFMA) and drops to 2 barriers per K-tile.
//
// Per-tile schedule (windows bounded by barriers; all guards tt-uniform):
//   w1: STAGE A(t+1)->buf^1 | read afA(kh0 r0-3), bf0 | MFMA p0 ‖ read afB(kh0 r4-7)
//       | MFMA p1 ‖ read bf1 | lgkmcnt(0) [bf1 has no pre-barrier consumer] | BAR
//   w2: STAGE B(t+2)->buf (B-region reads drained block-wide at BAR) | read afA2
//       (A-region, no conflict with B staging) | MFMA p2 ‖ read afB2 | MFMA p3
//       | vmcnt(4) [A(t+1),B(t+1) landed; B(t+2) in flight; tt>=46: drain] | BAR
// Race audit: every LDS region is re-written only after (a) all its reads were
// consumed by MFMA (per-wave lgkm drain) and (b) a barrier made that block-wide.
// vmcnt+barrier pairs make per-wave load-completion block-wide before any read
// of freshly staged data (reads of tile t's LDS happen only after tile t-1's
// end-of-tile VMW+BAR).
#define BAR8() __builtin_amdgcn_s_barrier()
#define VMW(N) do { asm volatile("s_waitcnt vmcnt(" #N ")" ::: "memory"); } while (0)
#define LGKW() do { asm volatile("s_waitcnt lgkmcnt(0)" ::: "memory"); } while (0)

#define LDA4(DST, MQ, KH, CUR) do { \
    const u16* un_ = lds_ + (CUR) * 32768; \
    _Pragma("unroll") \
    for (int i_ = 0; i_ < 4; ++i_) \
      (DST)[i_] = __builtin_bit_cast(bf16x8, \
          *(const short8*)(un_ + (wm * 128 + (MQ) * 64 + i_ * 16 + lrow) * 64 + pca[KH])); \
  } while (0)

#define LDB4(DST, KH, CUR) do { \
    const u16* un_ = lds_ + (CUR) * 32768 + 16384; \
    _Pragma("unroll") \
    for (int i_ = 0; i_ < 4; ++i_) \
      (DST)[i_] = __builtin_bit_cast(bf16x8, \
          *(const short8*)(un_ + (wn * 64 + i_ * 16 + lrow) * 64 + pca[KH])); \
  } while (0)

// 8 MFMAs: acc rows MQ4+I0..MQ4+I0+1, all 4 j
#define MFMA8(MQ4, I0, A_, B_) do { \
    __builtin_amdgcn_s_setprio(1); \
    _Pragma("unroll") \
    for (int i_ = (I0); i_ < (I0) + 2; ++i_) { \
      _Pragma("unroll") \
      for (int j_ = 0; j_ < 4; ++j_) \
        acc[(MQ4) + i_][j_] = __builtin_amdgcn_mfma_f32_16x16x32_bf16( \
            (A_)[i_], (B_)[j_], acc[(MQ4) + i_][j_], 0, 0, 0); \
    } \
    __builtin_amdgcn_s_setprio(0); \
  } while (0)

__global__ __launch_bounds__(512, 2) void gemm2_pipe(
    const u16* __restrict__ cbf, const u16* __restrict__ CC,
    const u16* __restrict__ Wm, const u16* __restrict__ Wbf,
    float* __restrict__ of, const float* __restrict__ bias) {
    __shared__ __align__(16) u16 lds_[65536];  // [buf2][A|B][row256][col64] = 128 KiB
    const int tid  = threadIdx.x;
    const int lane = tid & 63;
    const int wave = tid >> 6;          // 8 waves: 2 (M) x 4 (N)
    const int lin  = blockIdx.x;
    const int b    = lin & 7;           // XCD pin: one batch per XCD
    const int rem  = lin >> 3;          // 0..31 -> 8 m-tiles x 4 n-tiles
    const int n0   = (rem & 3) * 256;
    const int m0   = (rem >> 2) * 256;
    const int wm   = wave >> 2;         // 0..1  -> rows m0+wm*128 .. +127
    const int wn   = wave & 3;          // 0..3  -> cols n0+wn*64 .. +63
    const int quad = lane >> 4;
    const int lrow = lane & 15;
    const int lr7  = lane & 7;          // == row&7 for every fragment-read row
    // physical 16B chunk (u16 offset) for logical k-chunk (KH*4 + quad):
    const int pca[2] = { ((0 + quad) ^ lr7) * 8, ((4 + quad) ^ lr7) * 8 };

    const u16* Acb  = cbf + (size_t)b * (C_LEN * D_DIM);
    const u16* Acc0 = CC  + (size_t)b * (C_LEN * 2048);
    const u16* Acc1 = Acc0 + 1024;
    const u16* Bwm  = Wm  + (size_t)b * (D_DIM * D_DIM);

    // stage a full [256][64] unit (ab: 0=A,1=B) of tile tt into LDS buffer tt&1.
    // linear LDS dest (wave-uniform base; HW adds lane*16), inverse-swizzled source:
    // LDS[row][pchunk] = global[row][pchunk ^ (row&7)]  (8 chunks of 16B per row).
    auto STAGE = [&](int tt, int ab) {
        const int sec = tt >> 4;                    // 3 K-sections of 16 tiles
        const int kl  = (tt & 15) * 64;             // local k within section
        const u16* base;
        int r0;
        if (ab == 0) { base = (sec == 0) ? Acb : (sec == 1) ? Acc0 : Acc1; r0 = m0; }
        else         { base = (sec == 0) ? Bwm : (sec == 1) ? Wbf  : Wbf + 1024; r0 = n0; }
        const int ld = (sec == 0) ? 1024 : 2048;
        u16* unit = lds_ + (tt & 1) * 32768 + ab * 16384;
        #pragma unroll
        for (int l = 0; l < 4; ++l) {
            const int li  = l * 512 + tid;          // 0..2047 -> (row, chunk)
            const int row = li >> 3;
            const int sc  = (li & 7) ^ (row & 7);   // inverse swizzle on global col
            async16(base + (size_t)(r0 + row) * ld + kl + sc * 8,
                    unit + (size_t)(l * 512 + (tid & ~63)) * 8);
        }
    };

    floatx4 acc[8][4];
    #pragma unroll
    for (int i = 0; i < 8; ++i)
        #pragma unroll
        for (int j = 0; j < 4; ++j) acc[i][j] = (floatx4)(0.0f);

    // prologue: A(0), B(0), B(1); A(1) is staged in w1 of tile 0.
    STAGE(0, 0); STAGE(0, 1); STAGE(1, 1);
    VMW(4);                        // own A(0), B(0) landed; B(1) in flight
    BAR8();                        // -> block-wide visibility

    bf16x8 afA[4], afB[4], afA2[4], afB2[4], bf0[4], bf1[4];
    for (int tt = 0; tt < 48; ++tt) {
        const int cur = tt & 1;
        // ---------------- window 1 ----------------
        if (tt + 1 < 48) STAGE(tt + 1, 0);    // A(t+1) -> opposite buffer
        LDA4(afA, 0, 0, cur);                 // exposed reads (p0 frags)
        LDB4(bf0, 0, cur);
        MFMA8(0, 0, afA, bf0);
        LDA4(afB, 1, 0, cur);                 // p1 A-frags, hidden under p0
        MFMA8(0, 2, afA, bf0);
        MFMA8(4, 0, afB, bf0);
        LDB4(bf1, 1, cur);                    // p2 B-frags, hidden under p1
        MFMA8(4, 2, afB, bf0);
        LGKW();                               // drain bf1 (no pre-barrier consumer)
        BAR8();                               // all B(t)-region reads done block-wide
        // ---------------- window 2 ----------------
        if (tt + 2 < 48) STAGE(tt + 2, 1);    // B(t+2) -> same buffer (B-region free)
        LDA4(afA2, 0, 1, cur);                // p2 A-frags (A-region: no stage conflict)
        MFMA8(0, 0, afA2, bf1);
        LDA4(afB2, 1, 1, cur);                // p3 A-frags, hidden under p2
        MFMA8(0, 2, afA2, bf1);
        MFMA8(4, 0, afB2, bf1);
        MFMA8(4, 2, afB2, bf1);
        if (tt < 46) { VMW(4); } else { VMW(0); } // A(t+1)/B(t+1) landed; B(t+2) flies
        BAR8();                               // block-wide before tile t+1 reads
    }

    // ---- epilogue; C/D layout: col = lane&15, row = quad*4 + reg ----
    float bs[4];
    #pragma unroll
    for (int j = 0; j < 4; ++j) bs[j] = bias[n0 + wn * 64 + j * 16 + lrow];
    float* ofb = of + (size_t)b * (C_LEN * D_DIM);
    #pragma unroll
    for (int i = 0; i < 8; ++i) {
        #pragma unroll
        for (int j = 0; j < 4; ++j) {
            #pragma unroll
            for (int e = 0; e < 4; ++e) {
                const int gm = m0 + wm * 128 + i * 16 + quad * 4 + e;
                const int gn = n0 + wn * 64 + j * 16 + lrow;
                ofb[(size_t)gm * D_DIM + gn] = acc[i][j][e] + bs[j];
            }
        }
    }
}

// ---------- softmax over Q per (b,c) row; also record rowmax ----------
__global__ void softmax_kernel(const float* __restrict__ S, const float* __restrict__ colterm,
                               u16* __restrict__ P, float* __restrict__ mbuf) {
    int row = blockIdx.x * 4 + (threadIdx.x >> 6);
    int lane = threadIdx.x & 63;
    int b = row >> 11;  // C_LEN = 2048
    const float* sp = S + (size_t)row * Q_LEN;
    const float* cp = colterm + (size_t)b * Q_LEN;
    float v[8];
    float m = -1e30f;
    #pragma unroll
    for (int j = 0; j < 8; ++j) {
        int idx = j * 64 + lane;
        v[j] = sp[idx] + cp[idx];
        m = fmaxf(m, v[j]);
    }
    for (int off = 32; off; off >>= 1) m = fmaxf(m, __shfl_xor(m, off));
    float s = 0.f;
    #pragma unroll
    for (int j = 0; j < 8; ++j) { v[j] = __expf(v[j] - m); s += v[j]; }
    for (int off = 32; off; off >>= 1) s += __shfl_xor(s, off);
    float inv = 1.0f / s;
    u16* pp = P + (size_t)row * Q_LEN;
    #pragma unroll
    for (int j = 0; j < 8; ++j) pp[j * 64 + lane] = f2bf(v[j] * inv);
    if (lane == 0) mbuf[row] = m;
}

// ---------- b_att[b,c] = softmax_c(rowmax + rowterm) ----------
__global__ __launch_bounds__(256) void batt_kernel(const float* __restrict__ mbuf,
                                                   const float* __restrict__ rowterm,
                                                   float* __restrict__ batt) {
    __shared__ float red[8];
    int b = blockIdx.x;
    int tid = threadIdx.x;
    const float* mb = mbuf + (size_t)b * C_LEN;
    const float* rt = rowterm + (size_t)b * C_LEN;
    float v[8];
    float m = -1e30f;
    #pragma unroll
    for (int j = 0; j < 8; ++j) { int idx = j * 256 + tid; v[j] = mb[idx] + rt[idx]; m = fmaxf(m, v[j]); }
    for (int off = 32; off; off >>= 1) m = fmaxf(m, __shfl_xor(m, off));
    int wave = tid >> 6, lane = tid & 63;
    if (lane == 0) red[wave] = m;
    __syncthreads();
    m = fmaxf(fmaxf(red[0], red[1]), fmaxf(red[2], red[3]));
    float s = 0.f;
    #pragma unroll
    for (int j = 0; j < 8; ++j) { v[j] = __expf(v[j] - m); s += v[j]; }
    for (int off = 32; off; off >>= 1) s += __shfl_xor(s, off);
    if (lane == 0) red[4 + wave] = s;
    __syncthreads();
    s = red[4] + red[5] + red[6] + red[7];
    float inv = 1.0f / s;
    float* bb = batt + (size_t)b * C_LEN;
    #pragma unroll
    for (int j = 0; j < 8; ++j) bb[j * 256 + tid] = v[j] * inv;
}

// ---------- q2c[b,d] = sum_c b_att[b,c] * cbf[b,c,d] (chunked + atomic) ----------
__global__ __launch_bounds__(256) void q2c_kernel(const float* __restrict__ batt,
                                                  const u16* __restrict__ cbf,
                                                  float* __restrict__ q2c) {
    int d  = blockIdx.x * 256 + threadIdx.x;
    int b  = blockIdx.y;
    int c0 = blockIdx.z * 256;
    const u16* cb = cbf + ((size_t)b * C_LEN + c0) * D_DIM + d;
    const float* bb = batt + (size_t)b * C_LEN + c0;
    float s = 0.f;
    #pragma unroll 4
    for (int i = 0; i < 256; ++i) s += bb[i] * bf2f(cb[(size_t)i * D_DIM]);
    atomicAdd(&q2c[(size_t)b * D_DIM + d], s);
}

extern "C" void kernel_launch(void* const* d_in, const int* in_sizes, int n_in,
                              void* d_out, int out_size, void* d_ws, size_t ws_size,
                              hipStream_t stream) {
    const float* c   = (const float*)d_in[0];
    const float* q   = (const float*)d_in[1];
    const float* wcq = (const float*)d_in[2];
    // b_cq (d_in[3]), b_c (d_in[5]), b_q (d_in[7]) cancel in both softmaxes — unused.
    const float* w_c = (const float*)d_in[4];
    const float* w_q = (const float*)d_in[6];
    const float* W_l = (const float*)d_in[8];
    const float* b_l = (const float*)d_in[9];
    float* out = (float*)d_out;

    char* ws = (char*)d_ws;
    // Region plan (MiB), lifetime-safe re-use:
    //   [0,32)    cbf                       (prep .. gemm2)
    //   [32,96)   CC interleaved c2q|cc2q   (written gemm<1>, read gemm2)
    //             before gemm<1>: S fp32 @32..64, qwbf @64..72
    //   [96,112)  P bf16 (softmax..gemm<1>), then Wm (wmerge_all..gemm2)
    //   [112,120) qT (prep..gemm<1>), then Wbf compact 4MiB (wmerge_all..gemm2)
    //   [120,...) smalls
    u16*   cbf     = (u16*)ws;
    float* S       = (float*)(ws + 33554432);
    u16*   CC      = (u16*)(ws + 33554432);
    u16*   qwbf    = (u16*)(ws + 67108864);
    u16*   P       = (u16*)(ws + 100663296);
    u16*   Wm      = (u16*)(ws + 100663296);
    u16*   qT      = (u16*)(ws + 117440512);
    u16*   Wbf     = (u16*)(ws + 117440512);
    float* rowterm = (float*)(ws + 125829120);
    float* colterm = (float*)(ws + 125894656);
    float* mbuf    = (float*)(ws + 125911040);
    float* batt    = (float*)(ws + 125976576);
    float* q2c     = (float*)(ws + 126042112);   // total ~120.3 MiB

    prep_kernel<<<dim3(9248), dim3(256), 0, stream>>>(c, q, wcq, w_c, w_q,
                                                      cbf, qwbf, qT, rowterm, colterm, q2c);
    gemm_async<0><<<dim3(512), dim3(256), 0, stream>>>(cbf, nullptr, nullptr, qwbf, nullptr, S, nullptr, nullptr);
    softmax_kernel<<<dim3(4096), dim3(256), 0, stream>>>(S, colterm, P, mbuf);
    batt_kernel<<<dim3(8), dim3(256), 0, stream>>>(mbuf, rowterm, batt);
    q2c_kernel<<<dim3(4, 8, 8), dim3(256), 0, stream>>>(batt, cbf, q2c);
    gemm_async<1><<<dim3(1024), dim3(256), 0, stream>>>(P, cbf, nullptr, qT, nullptr, nullptr, CC, nullptr);
    wmerge_all<<<dim3(1024), dim3(256), 0, stream>>>(W_l, q2c, Wm, Wbf);
    gemm2_pipe<<<dim3(256), dim3(512), 0, stream>>>(cbf, CC, Wm, Wbf, out, b_l);
}

// Round 7
// 344.079 us; speedup vs baseline: 1.0569x; 1.0073x over previous
//
#include <hip/hip_runtime.h>

typedef unsigned short u16;
typedef __attribute__((ext_vector_type(4))) float floatx4;
typedef __attribute__((ext_vector_type(4))) unsigned short u16x4;
typedef __attribute__((ext_vector_type(8))) short short8;
typedef __attribute__((ext_vector_type(8))) __bf16 bf16x8;

#define B_SZ 8
#define C_LEN 2048
#define Q_LEN 512
#define D_DIM 1024
#define K4 (4 * D_DIM)

static __device__ __forceinline__ u16 f2bf(float f) {
    union { float f; unsigned int u; } v; v.f = f;
    unsigned int r = v.u + 0x7FFFu + ((v.u >> 16) & 1u);  // round-to-nearest-even
    return (u16)(r >> 16);
}
static __device__ __forceinline__ float bf2f(u16 h) {
    union { unsigned int u; float f; } v; v.u = ((unsigned int)h) << 16;
    return v.f;
}

// async global->LDS, 16B per lane; LDS dest = wave-uniform base + lane*16
static __device__ __forceinline__ void async16(const void* g, void* l) {
    __builtin_amdgcn_global_load_lds(
        (const __attribute__((address_space(1))) unsigned int*)g,
        (__attribute__((address_space(3))) unsigned int*)(unsigned int)(unsigned long long)l,
        16, 0, 0);
}

// ---------- fused prep: precast_c | precast_q | transpose_q | zero q2c ----------
__global__ __launch_bounds__(256) void prep_kernel(
    const float* __restrict__ c, const float* __restrict__ q,
    const float* __restrict__ w_cq, const float* __restrict__ w_c, const float* __restrict__ w_q,
    u16* __restrict__ cbf, u16* __restrict__ qwbf, u16* __restrict__ qT,
    float* __restrict__ rowterm, float* __restrict__ colterm, float* __restrict__ q2c) {
    int blk = blockIdx.x;
    int tid = threadIdx.x;
    if (blk < 4096) {
        // precast_c: cbf = bf16(c); rowterm = c . w_c
        int row = blk * 4 + (tid >> 6);
        int lane = tid & 63;
        const float* src = c + (size_t)row * D_DIM;
        u16* dst = cbf + (size_t)row * D_DIM;
        float s = 0.f;
        #pragma unroll
        for (int j = 0; j < 4; ++j) {
            int idx = j * 256 + lane * 4;
            floatx4 a = *(const floatx4*)(src + idx);
            floatx4 w = *(const floatx4*)(w_c + idx);
            s += a[0]*w[0] + a[1]*w[1] + a[2]*w[2] + a[3]*w[3];
            u16x4 o;
            #pragma unroll
            for (int e = 0; e < 4; ++e) o[e] = f2bf(a[e]);
            *(u16x4*)(dst + idx) = o;
        }
        for (int off = 32; off; off >>= 1) s += __shfl_down(s, off);
        if (lane == 0) rowterm[row] = s;
    } else if (blk < 5120) {
        // precast_q: qwbf = bf16(q .* w_cq); colterm = q . w_q
        int row = (blk - 4096) * 4 + (tid >> 6);
        int lane = tid & 63;
        const float* src = q + (size_t)row * D_DIM;
        u16* dst = qwbf + (size_t)row * D_DIM;
        float s = 0.f;
        #pragma unroll
        for (int j = 0; j < 4; ++j) {
            int idx = j * 256 + lane * 4;
            floatx4 a  = *(const floatx4*)(src + idx);
            floatx4 wc = *(const floatx4*)(w_cq + idx);
            floatx4 wq = *(const floatx4*)(w_q + idx);
            s += a[0]*wq[0] + a[1]*wq[1] + a[2]*wq[2] + a[3]*wq[3];
            u16x4 o;
            #pragma unroll
            for (int e = 0; e < 4; ++e) o[e] = f2bf(a[e] * wc[e]);
            *(u16x4*)(dst + idx) = o;
        }
        for (int off = 32; off; off >>= 1) s += __shfl_down(s, off);
        if (lane == 0) colterm[row] = s;
    } else if (blk < 9216) {
        // transpose_q: qT[b,d,q] = bf16(q[b,q,d])
        __shared__ float tile[32][33];
        int t = blk - 5120;
        int q0 = (t & 15) * 32;
        int d0 = ((t >> 4) & 31) * 32;
        int b = t >> 9;
        int tx = tid & 31, ty = tid >> 5;  // 32 x 8
        const float* qb = q + (size_t)b * Q_LEN * D_DIM;
        #pragma unroll
        for (int j = 0; j < 4; ++j) {
            int row = ty + j * 8;
            tile[row][tx] = qb[(size_t)(q0 + row) * D_DIM + d0 + tx];
        }
        __syncthreads();
        u16* qTb = qT + (size_t)b * D_DIM * Q_LEN;
        #pragma unroll
        for (int j = 0; j < 4; ++j) {
            int row = ty + j * 8;
            qTb[(size_t)(d0 + row) * Q_LEN + q0 + tx] = f2bf(tile[tx][row]);
        }
    } else {
        // zero q2c (8192 floats)
        int i = (blk - 9216) * 256 + tid;
        q2c[i] = 0.0f;
    }
}

// ---------- fused W prep: Wm[b,n,k] = bf16(W1 + W4*q2c); Wbf[n,kk] = bf16(W[n,1024+kk]) ----------
__global__ __launch_bounds__(256) void wmerge_all(const float* __restrict__ W, const float* __restrict__ q2c,
                                                  u16* __restrict__ Wm, u16* __restrict__ Wbf) {
    int n = blockIdx.x;             // 1024 rows
    int k = threadIdx.x * 4;        // 0..1023
    const float* wr = W + (size_t)n * K4;
    floatx4 w1 = *(const floatx4*)(wr + k);
    floatx4 w4 = *(const floatx4*)(wr + 3072 + k);
    #pragma unroll
    for (int p = 0; p < 2; ++p) {
        int kk = p * 1024 + k;
        floatx4 v = *(const floatx4*)(wr + 1024 + kk);
        u16x4 o;
        #pragma unroll
        for (int e = 0; e < 4; ++e) o[e] = f2bf(v[e]);
        *(u16x4*)(Wbf + (size_t)n * 2048 + kk) = o;
    }
    #pragma unroll
    for (int b = 0; b < 8; ++b) {
        floatx4 g = *(const floatx4*)(q2c + (size_t)b * D_DIM + k);
        u16x4 o;
        #pragma unroll
        for (int e = 0; e < 4; ++e) o[e] = f2bf(w1[e] + w4[e] * g[e]);
        *(u16x4*)(Wm + (size_t)b * 1048576 + (size_t)n * 1024 + k) = o;
    }
}

// ---------- unified async bf16 GEMM, C = A @ B^T, 128x128 tile, BK=64, swizzled LDS ----------
// (kept for MODE 0 and MODE 1; MODE 2 uses gemm2_1bar below)
template<int MODE>
__global__ __launch_bounds__(256) void gemm_async(
    const u16* __restrict__ A0, const u16* __restrict__ A1, const u16* __restrict__ A2,
    const u16* __restrict__ B0, const u16* __restrict__ B1,
    float* __restrict__ of, u16* __restrict__ ob, const float* __restrict__ bias) {
    constexpr int NSEC = (MODE == 2) ? 3 : 1;
    constexpr int KSEC = (MODE == 1) ? 512 : 1024;
    constexpr int LDO  = (MODE == 0) ? 512 : 1024;
    constexpr int NTILES = (MODE == 0) ? 4 : 8;
    __shared__ u16 As[128 * 64];
    __shared__ u16 Bs[128 * 64];
    const int tid  = threadIdx.x;
    const int lane = tid & 63;
    const int wave = tid >> 6;
    const int lin  = blockIdx.x;
    const int b    = lin & 7;            // XCD pin
    const int rem  = lin >> 3;
    const int n0   = (rem % NTILES) * 128;
    const int m0   = (rem / NTILES) * 128;

    const u16* Aarr[NSEC];
    const u16* Barr[NSEC];
    int lda_[NSEC], ldb_[NSEC];
    if constexpr (MODE == 0) {
        Aarr[0] = A0 + (size_t)b * C_LEN * D_DIM; lda_[0] = 1024;
        Barr[0] = B0 + (size_t)b * Q_LEN * D_DIM; ldb_[0] = 1024;
    } else if constexpr (MODE == 1) {
        Aarr[0] = A0 + (size_t)b * C_LEN * Q_LEN; lda_[0] = 512;
        Barr[0] = B0 + (size_t)b * D_DIM * Q_LEN; ldb_[0] = 512;
    } else {
        Aarr[0] = A0 + (size_t)b * C_LEN * D_DIM;  lda_[0] = 1024;
        Barr[0] = B0 + (size_t)b * D_DIM * D_DIM;  ldb_[0] = 1024;   // Wm (per-batch)
        Aarr[1] = A1 + (size_t)b * C_LEN * 2048;        lda_[1] = 2048;  // CC + 0
        Barr[1] = B1;                                   ldb_[1] = 2048;  // Wbf + 0
        Aarr[2] = A1 + (size_t)b * C_LEN * 2048 + 1024; lda_[2] = 2048;  // CC + 1024
        Barr[2] = B1 + 1024;                            ldb_[2] = 2048;  // Wbf + 1024
    }

    // staging geometry: 16 chunks of 8 rows; wave w stages chunks 4w..4w+3
    const int srow = lane >> 3;                    // 0..7 row-within-chunk
    const int ssc  = ((lane & 7) ^ srow) * 8;      // swizzled source column (u16)

    floatx4 acc[4][4];
    #pragma unroll
    for (int i = 0; i < 4; ++i)
        #pragma unroll
        for (int j = 0; j < 4; ++j)
            acc[i][j] = (floatx4)(0.0f);

    const int wrow = (wave >> 1) * 64;
    const int wcol = (wave & 1) * 64;
    const int quad = lane >> 4;
    const int lrow = lane & 15;
    const int sw7  = lane & 7;                     // row&7 for all reader rows

    #pragma unroll
    for (int sec = 0; sec < NSEC; ++sec) {
        const u16* __restrict__ Ab = Aarr[sec];
        const u16* __restrict__ Bb = Barr[sec];
        const int LA = lda_[sec];
        const int LB = ldb_[sec];
        for (int k0 = 0; k0 < KSEC; k0 += 64) {
            #pragma unroll
            for (int cc = 0; cc < 4; ++cc) {
                int ch = wave * 4 + cc;
                int rr = ch * 8 + srow;
                async16(Ab + (size_t)(m0 + rr) * LA + k0 + ssc, &As[ch * 512]);
            }
            #pragma unroll
            for (int cc = 0; cc < 4; ++cc) {
                int ch = wave * 4 + cc;
                int rr = ch * 8 + srow;
                async16(Bb + (size_t)(n0 + rr) * LB + k0 + ssc, &Bs[ch * 512]);
            }
            __syncthreads();
            #pragma unroll
            for (int h = 0; h < 2; ++h) {
                const int pc = ((h * 4 + quad) ^ sw7) * 8;   // physical column (u16)
                bf16x8 af[4], bfr[4];
                #pragma unroll
                for (int i = 0; i < 4; ++i)
                    af[i] = __builtin_bit_cast(bf16x8, *(const short8*)&As[(wrow + i*16 + lrow) * 64 + pc]);
                #pragma unroll
                for (int j = 0; j < 4; ++j)
                    bfr[j] = __builtin_bit_cast(bf16x8, *(const short8*)&Bs[(wcol + j*16 + lrow) * 64 + pc]);
                #pragma unroll
                for (int i = 0; i < 4; ++i)
                    #pragma unroll
                    for (int j = 0; j < 4; ++j)
                        acc[i][j] = __builtin_amdgcn_mfma_f32_16x16x32_bf16(af[i], bfr[j], acc[i][j], 0, 0, 0);
            }
            __syncthreads();
        }
    }

    // ---- epilogue; C/D layout: col = lane&15, row = quad*4 + reg ----
    float* ofb = nullptr; u16* ccb = nullptr; const u16* cbr = nullptr;
    if (MODE == 0)      ofb = of + (size_t)b * C_LEN * Q_LEN;
    else if (MODE == 1) { ccb = ob + (size_t)b * C_LEN * 2048; cbr = A1 + (size_t)b * C_LEN * D_DIM; }
    else                ofb = of + (size_t)b * C_LEN * D_DIM;
    #pragma unroll
    for (int i = 0; i < 4; ++i) {
        #pragma unroll
        for (int j = 0; j < 4; ++j) {
            #pragma unroll
            for (int e = 0; e < 4; ++e) {
                int gm = m0 + wrow + i * 16 + quad * 4 + e;
                int gn = n0 + wcol + j * 16 + lrow;
                float v = acc[i][j][e];
                if (MODE == 0)      ofb[(size_t)gm * LDO + gn] = v;
                else if (MODE == 1) {
                    u16 p = f2bf(v);
                    float cv = bf2f(cbr[(size_t)gm * 1024 + gn]);
                    ccb[(size_t)gm * 2048 + gn]        = p;
                    ccb[(size_t)gm * 2048 + 1024 + gn] = f2bf(cv * bf2f(p));
                }
                else                ofb[(size_t)gm * LDO + gn] = v + bias[gn];
            }
        }
    }
}

// ---------- 256x256-tile, ONE-barrier/tile bf16 GEMM for the output projection ----------
// z[b] = cbf[b] @ Wm[b]^T + CC0[b] @ Wbf0^T + CC1[b] @ Wbf1^T + b_l   (K = 3*1024 = 48 tiles of 64)
//
// Round-6 postmortem: measured 4880 cyc/tile == MFMA-pipe (2480) + LDS-pipe (2300)
// exactly — the 2-window schedule serialized the two CU-level pipes (every ds_read
// behind a barrier the MFMAs also wait on; LGKW drained the read backlog while the
// matrix pipe idled). This version: ONE barrier per tile, no LGKW, no mid-window.
// All 24 frag reads issue early; the LDS pipe services them UNDER the 64-MFMA
// window (compiler's fine-grained lgkmcnt interleave). Stage both A(t+1),B(t+1)
// at tile start into the opposite buffer; VMW(0) at tile end has a full tile
// (~2400 cyc) of slack over L2/HBM latency.
//
// Race audit:
//   * STAGE(t+1)->buf^1: buf^1's tile t-1 reads were all consumed by MFMAs before
//     BAR(t-1) (compiler lgkm-before-consumer), block-wide via that barrier; the
//     stage is issued after BAR(t-1) in program order. No W-A-R.
//   * Reads of tile t (buf) vs stage of t+1 (buf^1): disjoint regions.
//   * VMW(0)+BAR at tile end: staged data landed + block-wide visible before any
//     tile t+1 read. Single barrier per tile bounds wave skew to one tile.
#define BAR8() __builtin_amdgcn_s_barrier()
#define VMW(N) do { asm volatile("s_waitcnt vmcnt(" #N ")" ::: "memory"); } while (0)

#define LDA4(DST, MQ, KH, CUR) do { \
    const u16* un_ = lds_ + (CUR) * 32768; \
    _Pragma("unroll") \
    for (int i_ = 0; i_ < 4; ++i_) \
      (DST)[i_] = __builtin_bit_cast(bf16x8, \
          *(const short8*)(un_ + (wm * 128 + (MQ) * 64 + i_ * 16 + lrow) * 64 + pca[KH])); \
  } while (0)

#define LDB4(DST, KH, CUR) do { \
    const u16* un_ = lds_ + (CUR) * 32768 + 16384; \
    _Pragma("unroll") \
    for (int i_ = 0; i_ < 4; ++i_) \
      (DST)[i_] = __builtin_bit_cast(bf16x8, \
          *(const short8*)(un_ + (wn * 64 + i_ * 16 + lrow) * 64 + pca[KH])); \
  } while (0)

// 8 MFMAs: acc rows MQ4+I0..MQ4+I0+1, all 4 j
#define MFMA8(MQ4, I0, A_, B_) do { \
    __builtin_amdgcn_s_setprio(1); \
    _Pragma("unroll") \
    for (int i_ = (I0); i_ < (I0) + 2; ++i_) { \
      _Pragma("unroll") \
      for (int j_ = 0; j_ < 4; ++j_) \
        acc[(MQ4) + i_][j_] = __builtin_amdgcn_mfma_f32_16x16x32_bf16( \
            (A_)[i_], (B_)[j_], acc[(MQ4) + i_][j_], 0, 0, 0); \
    } \
    __builtin_amdgcn_s_setprio(0); \
  } while (0)

__global__ __launch_bounds__(512, 2) void gemm2_1bar(
    const u16* __restrict__ cbf, const u16* __restrict__ CC,
    const u16* __restrict__ Wm, const u16* __restrict__ Wbf,
    float* __restrict__ of, const float* __restrict__ bias) {
    __shared__ __align__(16) u16 lds_[65536];  // [buf2][A|B][row256][col64] = 128 KiB
    const int tid  = threadIdx.x;
    const int lane = tid & 63;
    const int wave = tid >> 6;          // 8 waves: 2 (M) x 4 (N)
    const int lin  = blockIdx.x;
    const int b    = lin & 7;           // XCD pin: one batch per XCD
    const int rem  = lin >> 3;          // 0..31 -> 8 m-tiles x 4 n-tiles
    const int n0   = (rem & 3) * 256;
    const int m0   = (rem >> 2) * 256;
    const int wm   = wave >> 2;         // 0..1  -> rows m0+wm*128 .. +127
    const int wn   = wave & 3;          // 0..3  -> cols n0+wn*64 .. +63
    const int quad = lane >> 4;
    const int lrow = lane & 15;
    const int lr7  = lane & 7;          // == row&7 for every fragment-read row
    // physical 16B chunk (u16 offset) for logical k-chunk (KH*4 + quad):
    const int pca[2] = { ((0 + quad) ^ lr7) * 8, ((4 + quad) ^ lr7) * 8 };

    const u16* Acb  = cbf + (size_t)b * (C_LEN * D_DIM);
    const u16* Acc0 = CC  + (size_t)b * (C_LEN * 2048);
    const u16* Acc1 = Acc0 + 1024;
    const u16* Bwm  = Wm  + (size_t)b * (D_DIM * D_DIM);

    // stage a full [256][64] unit (ab: 0=A,1=B) of tile tt into LDS buffer tt&1.
    // linear LDS dest (wave-uniform base; HW adds lane*16), inverse-swizzled source:
    // LDS[row][pchunk] = global[row][pchunk ^ (row&7)]  (8 chunks of 16B per row).
    auto STAGE = [&](int tt, int ab) {
        const int sec = tt >> 4;                    // 3 K-sections of 16 tiles
        const int kl  = (tt & 15) * 64;             // local k within section
        const u16* base;
        int r0;
        if (ab == 0) { base = (sec == 0) ? Acb : (sec == 1) ? Acc0 : Acc1; r0 = m0; }
        else         { base = (sec == 0) ? Bwm : (sec == 1) ? Wbf  : Wbf + 1024; r0 = n0; }
        const int ld = (sec == 0) ? 1024 : 2048;
        u16* unit = lds_ + (tt & 1) * 32768 + ab * 16384;
        #pragma unroll
        for (int l = 0; l < 4; ++l) {
            const int li  = l * 512 + tid;          // 0..2047 -> (row, chunk)
            const int row = li >> 3;
            const int sc  = (li & 7) ^ (row & 7);   // inverse swizzle on global col
            async16(base + (size_t)(r0 + row) * ld + kl + sc * 8,
                    unit + (size_t)(l * 512 + (tid & ~63)) * 8);
        }
    };

    floatx4 acc[8][4];
    #pragma unroll
    for (int i = 0; i < 8; ++i)
        #pragma unroll
        for (int j = 0; j < 4; ++j) acc[i][j] = (floatx4)(0.0f);

    // prologue: stage tile 0 into buf0; tile 1 is staged inside tile 0's body.
    STAGE(0, 0); STAGE(0, 1);
    VMW(0);
    BAR8();

    bf16x8 afA[4], afB[4], afA2[4], afB2[4], bf0[4], bf1[4];
    for (int tt = 0; tt < 48; ++tt) {
        const int cur = tt & 1;
        // stage next tile (both panels) into the opposite buffer, issued first so
        // the loads fly under this tile's MFMA window.
        if (tt + 1 < 48) { STAGE(tt + 1, 0); STAGE(tt + 1, 1); }
        // all 24 fragment reads from the current buffer — issued before/between
        // the MFMA clusters; LDS pipe drains them under the matrix window.
        LDA4(afA, 0, 0, cur);
        LDB4(bf0, 0, cur);
        LDA4(afB, 1, 0, cur);
        LDA4(afA2, 0, 1, cur);
        LDB4(bf1, 1, cur);
        LDA4(afB2, 1, 1, cur);
        // 64 MFMAs; compiler inserts fine-grained lgkmcnt waits per cluster.
        MFMA8(0, 0, afA, bf0);
        MFMA8(0, 2, afA, bf0);
        MFMA8(4, 0, afB, bf0);
        MFMA8(4, 2, afB, bf0);
        MFMA8(0, 0, afA2, bf1);
        MFMA8(0, 2, afA2, bf1);
        MFMA8(4, 0, afB2, bf1);
        MFMA8(4, 2, afB2, bf1);
        // staged loads were issued a full tile (~2400 cyc) ago: cheap drain.
        VMW(0);
        BAR8();
    }

    // ---- epilogue; C/D layout: col = lane&15, row = quad*4 + reg ----
    float bs[4];
    #pragma unroll
    for (int j = 0; j < 4; ++j) bs[j] = bias[n0 + wn * 64 + j * 16 + lrow];
    float* ofb = of + (size_t)b * (C_LEN * D_DIM);
    #pragma unroll
    for (int i = 0; i < 8; ++i) {
        #pragma unroll
        for (int j = 0; j < 4; ++j) {
            #pragma unroll
            for (int e = 0; e < 4; ++e) {
                const int gm = m0 + wm * 128 + i * 16 + quad * 4 + e;
                const int gn = n0 + wn * 64 + j * 16 + lrow;
                ofb[(size_t)gm * D_DIM + gn] = acc[i][j][e] + bs[j];
            }
        }
    }
}

// ---------- softmax over Q per (b,c) row; also record rowmax ----------
__global__ void softmax_kernel(const float* __restrict__ S, const float* __restrict__ colterm,
                               u16* __restrict__ P, float* __restrict__ mbuf) {
    int row = blockIdx.x * 4 + (threadIdx.x >> 6);
    int lane = threadIdx.x & 63;
    int b = row >> 11;  // C_LEN = 2048
    const float* sp = S + (size_t)row * Q_LEN;
    const float* cp = colterm + (size_t)b * Q_LEN;
    float v[8];
    float m = -1e30f;
    #pragma unroll
    for (int j = 0; j < 8; ++j) {
        int idx = j * 64 + lane;
        v[j] = sp[idx] + cp[idx];
        m = fmaxf(m, v[j]);
    }
    for (int off = 32; off; off >>= 1) m = fmaxf(m, __shfl_xor(m, off));
    float s = 0.f;
    #pragma unroll
    for (int j = 0; j < 8; ++j) { v[j] = __expf(v[j] - m); s += v[j]; }
    for (int off = 32; off; off >>= 1) s += __shfl_xor(s, off);
    float inv = 1.0f / s;
    u16* pp = P + (size_t)row * Q_LEN;
    #pragma unroll
    for (int j = 0; j < 8; ++j) pp[j * 64 + lane] = f2bf(v[j] * inv);
    if (lane == 0) mbuf[row] = m;
}

// ---------- b_att[b,c] = softmax_c(rowmax + rowterm) ----------
__global__ __launch_bounds__(256) void batt_kernel(const float* __restrict__ mbuf,
                                                   const float* __restrict__ rowterm,
                                                   float* __restrict__ batt) {
    __shared__ float red[8];
    int b = blockIdx.x;
    int tid = threadIdx.x;
    const float* mb = mbuf + (size_t)b * C_LEN;
    const float* rt = rowterm + (size_t)b * C_LEN;
    float v[8];
    float m = -1e30f;
    #pragma unroll
    for (int j = 0; j < 8; ++j) { int idx = j * 256 + tid; v[j] = mb[idx] + rt[idx]; m = fmaxf(m, v[j]); }
    for (int off = 32; off; off >>= 1) m = fmaxf(m, __shfl_xor(m, off));
    int wave = tid >> 6, lane = tid & 63;
    if (lane == 0) red[wave] = m;
    __syncthreads();
    m = fmaxf(fmaxf(red[0], red[1]), fmaxf(red[2], red[3]));
    float s = 0.f;
    #pragma unroll
    for (int j = 0; j < 8; ++j) { v[j] = __expf(v[j] - m); s += v[j]; }
    for (int off = 32; off; off >>= 1) s += __shfl_xor(s, off);
    if (lane == 0) red[4 + wave] = s;
    __syncthreads();
    s = red[4] + red[5] + red[6] + red[7];
    float inv = 1.0f / s;
    float* bb = batt + (size_t)b * C_LEN;
    #pragma unroll
    for (int j = 0; j < 8; ++j) bb[j * 256 + tid] = v[j] * inv;
}

// ---------- q2c[b,d] = sum_c b_att[b,c] * cbf[b,c,d] (chunked + atomic) ----------
__global__ __launch_bounds__(256) void q2c_kernel(const float* __restrict__ batt,
                                                  const u16* __restrict__ cbf,
                                                  float* __restrict__ q2c) {
    int d  = blockIdx.x * 256 + threadIdx.x;
    int b  = blockIdx.y;
    int c0 = blockIdx.z * 256;
    const u16* cb = cbf + ((size_t)b * C_LEN + c0) * D_DIM + d;
    const float* bb = batt + (size_t)b * C_LEN + c0;
    float s = 0.f;
    #pragma unroll 4
    for (int i = 0; i < 256; ++i) s += bb[i] * bf2f(cb[(size_t)i * D_DIM]);
    atomicAdd(&q2c[(size_t)b * D_DIM + d], s);
}

extern "C" void kernel_launch(void* const* d_in, const int* in_sizes, int n_in,
                              void* d_out, int out_size, void* d_ws, size_t ws_size,
                              hipStream_t stream) {
    const float* c   = (const float*)d_in[0];
    const float* q   = (const float*)d_in[1];
    const float* wcq = (const float*)d_in[2];
    // b_cq (d_in[3]), b_c (d_in[5]), b_q (d_in[7]) cancel in both softmaxes — unused.
    const float* w_c = (const float*)d_in[4];
    const float* w_q = (const float*)d_in[6];
    const float* W_l = (const float*)d_in[8];
    const float* b_l = (const float*)d_in[9];
    float* out = (float*)d_out;

    char* ws = (char*)d_ws;
    // Region plan (MiB), lifetime-safe re-use:
    //   [0,32)    cbf                       (prep .. gemm2)
    //   [32,96)   CC interleaved c2q|cc2q   (written gemm<1>, read gemm2)
    //             before gemm<1>: S fp32 @32..64, qwbf @64..72
    //   [96,112)  P bf16 (softmax..gemm<1>), then Wm (wmerge_all..gemm2)
    //   [112,120) qT (prep..gemm<1>), then Wbf compact 4MiB (wmerge_all..gemm2)
    //   [120,...) smalls
    u16*   cbf     = (u16*)ws;
    float* S       = (float*)(ws + 33554432);
    u16*   CC      = (u16*)(ws + 33554432);
    u16*   qwbf    = (u16*)(ws + 67108864);
    u16*   P       = (u16*)(ws + 100663296);
    u16*   Wm      = (u16*)(ws + 100663296);
    u16*   qT      = (u16*)(ws + 117440512);
    u16*   Wbf     = (u16*)(ws + 117440512);
    float* rowterm = (float*)(ws + 125829120);
    float* colterm = (float*)(ws + 125894656);
    float* mbuf    = (float*)(ws + 125911040);
    float* batt    = (float*)(ws + 125976576);
    float* q2c     = (float*)(ws + 126042112);   // total ~120.3 MiB

    prep_kernel<<<dim3(9248), dim3(256), 0, stream>>>(c, q, wcq, w_c, w_q,
                                                      cbf, qwbf, qT, rowterm, colterm, q2c);
    gemm_async<0><<<dim3(512), dim3(256), 0, stream>>>(cbf, nullptr, nullptr, qwbf, nullptr, S, nullptr, nullptr);
    softmax_kernel<<<dim3(4096), dim3(256), 0, stream>>>(S, colterm, P, mbuf);
    batt_kernel<<<dim3(8), dim3(256), 0, stream>>>(mbuf, rowterm, batt);
    q2c_kernel<<<dim3(4, 8, 8), dim3(256), 0, stream>>>(batt, cbf, q2c);
    gemm_async<1><<<dim3(1024), dim3(256), 0, stream>>>(P, cbf, nullptr, qT, nullptr, nullptr, CC, nullptr);
    wmerge_all<<<dim3(1024), dim3(256), 0, stream>>>(W_l, q2c, Wm, Wbf);
    gemm2_1bar<<<dim3(256), dim3(512), 0, stream>>>(cbf, CC, Wm, Wbf, out, b_l);
}